// Round 18
// baseline (160.603 us; speedup 1.0000x reference)
//
#include <hip/hip_runtime.h>
#include <math.h>

#define NB 4
#define NC 64
#define NN 4096
#define NH 4

typedef __attribute__((ext_vector_type(8))) short bf16x8;
typedef __attribute__((ext_vector_type(4))) float f32x4;

// ---------- RNE float -> bf16 bits ----------
__device__ __forceinline__ unsigned int bf16rne(float v) {
    unsigned int u = __float_as_uint(v);
    return (u + 0x7fffu + ((u >> 16) & 1u)) >> 16;
}

// ---------- top-5 insert, depth-2 med3 form ----------
__device__ __forceinline__ void ins5k(unsigned int (&tk)[5], unsigned int key) {
    unsigned int n0 = max(tk[0], key);
    unsigned int n1 = min(tk[0], max(tk[1], key));
    unsigned int n2 = min(tk[1], max(tk[2], key));
    unsigned int n3 = min(tk[2], max(tk[3], key));
    unsigned int n4 = min(tk[3], max(tk[4], key));
    tk[0]=n0; tk[1]=n1; tk[2]=n2; tk[3]=n3; tk[4]=n4;
}

// ---------- split helper: 8 floats -> hi uint4 + lo uint4 ----------
__device__ __forceinline__ void split8(const float* v, uint4& hw4, uint4& lw4) {
    unsigned int hw[4], lw[4];
    #pragma unroll
    for (int p = 0; p < 4; ++p) {
        float v0 = v[p*2], v1 = v[p*2+1];
        unsigned int h0 = bf16rne(v0), h1 = bf16rne(v1);
        float r0 = v0 - __uint_as_float(h0 << 16);
        float r1 = v1 - __uint_as_float(h1 << 16);
        unsigned int l0 = bf16rne(r0), l1 = bf16rne(r1);
        hw[p] = h0 | (h1 << 16);
        lw[p] = l0 | (l1 << 16);
    }
    hw4 = make_uint4(hw[0], hw[1], hw[2], hw[3]);
    lw4 = make_uint4(lw[0], lw[1], lw[2], lw[3]);
}

// ---------- K0: xsplit (4 waves/64-node group) + nrm + weight split ----------
__global__ __launch_bounds__(256) void k_pre(
    const float* __restrict__ x,
    const float* __restrict__ wk, const float* __restrict__ wq, const float* __restrict__ wv,
    unsigned short* __restrict__ hl, float* __restrict__ nrm,
    unsigned short* __restrict__ wsb)
{
    __shared__ float redn[4][64];
    int blk = blockIdx.x;
    int t = threadIdx.x;
    if (blk >= 256) {   // ---- weight split ----
        int r = (blk - 256)*256 + t;     // 0..767
        int mat = r >> 8, oc = r & 255;
        const float* wsrc = (mat==0) ? wk : ((mat==1) ? wq : wv);
        float wrow[64];
        #pragma unroll
        for (int g = 0; g < 16; ++g)
            *(float4*)&wrow[g*4] = *(const float4*)(wsrc + (size_t)oc*64 + g*4);
        unsigned short* wo = wsb + (size_t)r*128;
        #pragma unroll
        for (int g = 0; g < 8; ++g) {
            uint4 hw4, lw4;
            split8(&wrow[g*8], hw4, lw4);
            *(uint4*)(wo + g*8)      = hw4;
            *(uint4*)(wo + 64 + g*8) = lw4;
        }
        return;
    }
    // ---- xsplit ----
    int lane = t & 63, g = t >> 6;
    int node = blk*64 + lane;                    // flat (b,n); batch-aligned blocks
    const float* xb = x + ((size_t)(node >> 12))*NC*NN + (node & (NN-1));
    float vals[16];
    float ss = 0.f;
    #pragma unroll
    for (int i = 0; i < 16; ++i) {
        vals[i] = xb[(size_t)(g*16 + i)*NN];
        ss += vals[i]*vals[i];
    }
    redn[g][lane] = ss;
    __syncthreads();
    float st = redn[0][lane] + redn[1][lane] + redn[2][lane] + redn[3][lane];
    float rn = 1.f / fmaxf(sqrtf(st), 1e-12f);
    if (g == 0) nrm[node] = sqrtf(st);
    float nv[16];
    #pragma unroll
    for (int i = 0; i < 16; ++i) nv[i] = vals[i] * rn;
    unsigned short* ho = hl + (size_t)node*128 + g*16;
    #pragma unroll
    for (int gg = 0; gg < 2; ++gg) {
        uint4 hw4, lw4;
        split8(&nv[gg*8], hw4, lw4);
        *(uint4*)(ho + gg*8)      = hw4;
        *(uint4*)(ho + 64 + gg*8) = lw4;
    }
}

// ---------- qkv body: MFMA projections from hlb (W·x = nrm·(W·xn)) ----------
__device__ __forceinline__ void qkv_body(int blk,
    const unsigned short* __restrict__ hl, const float* __restrict__ nrm,
    const unsigned short* __restrict__ wsb,
    const float* __restrict__ bk, const float* __restrict__ bq, const float* __restrict__ bv,
    float* __restrict__ qo, float* __restrict__ ko, float* __restrict__ vo)
{
    int nt  = blk & 63;
    int rem = blk >> 6;          // 0..11
    int mat = rem % 3, b = rem / 3;
    const float* bias = (mat==0) ? bk : ((mat==1) ? bq : bv);
    float* outp       = (mat==0) ? ko : ((mat==1) ? qo : vo);
    int t = threadIdx.x, lane = t & 63, h = t >> 6;
    int ln = lane & 15, kh = lane >> 4;

    bf16x8 ah0[4], ah1[4], al0[4], al1[4];
    const unsigned short* wb2 = wsb + ((size_t)(mat*256 + h*64 + ln))*128 + kh*8;
    #pragma unroll
    for (int s = 0; s < 4; ++s) {
        const unsigned short* p = wb2 + (size_t)s*16*128;
        ah0[s] = *(const bf16x8*)(p);
        ah1[s] = *(const bf16x8*)(p + 32);
        al0[s] = *(const bf16x8*)(p + 64);
        al1[s] = *(const bf16x8*)(p + 96);
    }
    float4 bj[4];
    #pragma unroll
    for (int s = 0; s < 4; ++s) bj[s] = *(const float4*)(bias + h*64 + s*16 + kh*4);

    int n0base = nt*64;
    const unsigned short* xb2 = hl + ((size_t)b*NN + n0base + ln)*128 + kh*8;
    #pragma unroll
    for (int j = 0; j < 4; ++j) {
        const unsigned short* p = xb2 + (size_t)j*16*128;
        bf16x8 bh0 = *(const bf16x8*)(p);
        bf16x8 bh1 = *(const bf16x8*)(p + 32);
        bf16x8 bl0 = *(const bf16x8*)(p + 64);
        bf16x8 bl1 = *(const bf16x8*)(p + 96);
        int n = n0base + j*16 + ln;
        float sc = nrm[(size_t)b*NN + n];
        f32x4 av[4];
        #pragma unroll
        for (int s = 0; s < 4; ++s) {
            f32x4 acc = {0.f, 0.f, 0.f, 0.f};
            acc = __builtin_amdgcn_mfma_f32_16x16x32_bf16(ah0[s], bh0, acc, 0,0,0);
            acc = __builtin_amdgcn_mfma_f32_16x16x32_bf16(ah1[s], bh1, acc, 0,0,0);
            acc = __builtin_amdgcn_mfma_f32_16x16x32_bf16(al0[s], bh0, acc, 0,0,0);
            acc = __builtin_amdgcn_mfma_f32_16x16x32_bf16(al1[s], bh1, acc, 0,0,0);
            acc = __builtin_amdgcn_mfma_f32_16x16x32_bf16(ah0[s], bl0, acc, 0,0,0);
            acc = __builtin_amdgcn_mfma_f32_16x16x32_bf16(ah1[s], bl1, acc, 0,0,0);
            av[s][0] = acc[0]*sc + bj[s].x;
            av[s][1] = acc[1]*sc + bj[s].y;
            av[s][2] = acc[2]*sc + bj[s].z;
            av[s][3] = acc[3]*sc + bj[s].w;
        }
        float* ob = outp + (((size_t)(b*NH + h))*NN + n)*64 + kh*4;
        if (mat != 2) {
            float ss = 0.f;
            #pragma unroll
            for (int s = 0; s < 4; ++s)
                ss += av[s][0]*av[s][0] + av[s][1]*av[s][1]
                    + av[s][2]*av[s][2] + av[s][3]*av[s][3];
            ss += __shfl_xor(ss, 16);
            ss += __shfl_xor(ss, 32);
            float rn = 1.f / fmaxf(sqrtf(ss), 1e-12f);
            #pragma unroll
            for (int s = 0; s < 4; ++s)
                *(float4*)(ob + s*16) = make_float4(av[s][0]*rn, av[s][1]*rn,
                                                    av[s][2]*rn, av[s][3]*rn);
        } else {
            #pragma unroll
            for (int s = 0; s < 4; ++s)
                *(float4*)(ob + s*16) = make_float4(av[s][0], av[s][1],
                                                    av[s][2], av[s][3]);
        }
    }
}

// ---------- topk body: MFMA split-bf16 sim + packed-key top-5 (r15 structure) ----------
__device__ __forceinline__ void ctile(const bf16x8& ah0, const bf16x8& ah1,
                                      const bf16x8& al0, const bf16x8& al1,
                                      const bf16x8& bh0, const bf16x8& bh1,
                                      const bf16x8& bl0, const bf16x8& bl1,
                                      unsigned int (&tk)[4][5], unsigned int inv)
{
    f32x4 accP = {2.0f, 2.0f, 2.0f, 2.0f};   // pack bias pre-seeded
    f32x4 accQ = {0.f, 0.f, 0.f, 0.f};
    f32x4 accR = {0.f, 0.f, 0.f, 0.f};
    accP = __builtin_amdgcn_mfma_f32_16x16x32_bf16(ah0, bh0, accP, 0,0,0);
    accQ = __builtin_amdgcn_mfma_f32_16x16x32_bf16(al0, bh0, accQ, 0,0,0);
    accR = __builtin_amdgcn_mfma_f32_16x16x32_bf16(ah0, bl0, accR, 0,0,0);
    accP = __builtin_amdgcn_mfma_f32_16x16x32_bf16(ah1, bh1, accP, 0,0,0);
    accQ = __builtin_amdgcn_mfma_f32_16x16x32_bf16(al1, bh1, accQ, 0,0,0);
    accR = __builtin_amdgcn_mfma_f32_16x16x32_bf16(ah1, bl1, accR, 0,0,0);
    #pragma unroll
    for (int r = 0; r < 4; ++r) {
        float v = (accP[r] + accQ[r]) + accR[r];
        unsigned int key = (__float_as_uint(v) & 0xFFFFF000u) | inv;
        ins5k(tk[r], key);
    }
}

__device__ __forceinline__ void topk_body(int blk,
    const unsigned short* __restrict__ hl, unsigned int* __restrict__ pk)
{
    int cs = blk & 7;
    int rg = (blk >> 3) & 15;
    int b  = blk >> 7;
    int t = threadIdx.x, lane = t & 63, wave = t >> 6;
    int ln = lane & 15, kh = lane >> 4;
    const unsigned short* hb = hl + (size_t)b*NN*128;

    const unsigned short* ap0 = hb + (size_t)(rg*256 + wave*64 + ln)*128 + kh*8;
    bf16x8 a0h0 = *(const bf16x8*)(ap0);
    bf16x8 a0h1 = *(const bf16x8*)(ap0 + 32);
    bf16x8 a0l0 = *(const bf16x8*)(ap0 + 64);
    bf16x8 a0l1 = *(const bf16x8*)(ap0 + 96);
    const unsigned short* ap1 = ap0 + 16*128;
    bf16x8 a1h0 = *(const bf16x8*)(ap1);
    bf16x8 a1h1 = *(const bf16x8*)(ap1 + 32);
    bf16x8 a1l0 = *(const bf16x8*)(ap1 + 64);
    bf16x8 a1l1 = *(const bf16x8*)(ap1 + 96);
    const unsigned short* ap2 = ap0 + 32*128;
    bf16x8 a2h0 = *(const bf16x8*)(ap2);
    bf16x8 a2h1 = *(const bf16x8*)(ap2 + 32);
    bf16x8 a2l0 = *(const bf16x8*)(ap2 + 64);
    bf16x8 a2l1 = *(const bf16x8*)(ap2 + 96);
    const unsigned short* ap3 = ap0 + 48*128;
    bf16x8 a3h0 = *(const bf16x8*)(ap3);
    bf16x8 a3h1 = *(const bf16x8*)(ap3 + 32);
    bf16x8 a3l0 = *(const bf16x8*)(ap3 + 64);
    bf16x8 a3l1 = *(const bf16x8*)(ap3 + 96);

    unsigned int tk0[4][5], tk1[4][5], tk2[4][5], tk3[4][5];
    #pragma unroll
    for (int r=0;r<4;++r)
        #pragma unroll
        for (int kk=0;kk<5;++kk) { tk0[r][kk]=0u; tk1[r][kk]=0u; tk2[r][kk]=0u; tk3[r][kk]=0u; }

    int colbase = cs*512;
    unsigned int inv0 = 4095u - (unsigned int)(colbase + ln);

    const unsigned short* bp = hb + (size_t)(colbase + ln)*128 + kh*8;
    bf16x8 Ah0 = *(const bf16x8*)(bp);
    bf16x8 Ah1 = *(const bf16x8*)(bp + 32);
    bf16x8 Al0 = *(const bf16x8*)(bp + 64);
    bf16x8 Al1 = *(const bf16x8*)(bp + 96);
    bf16x8 Bh0, Bh1, Bl0, Bl1;

    for (int t5 = 0; t5 < 32; t5 += 2) {
        {   // prefetch t5+1
            const unsigned short* p = bp + (size_t)(t5+1)*16*128;
            Bh0 = *(const bf16x8*)(p);
            Bh1 = *(const bf16x8*)(p + 32);
            Bl0 = *(const bf16x8*)(p + 64);
            Bl1 = *(const bf16x8*)(p + 96);
        }
        {
            unsigned int inv = inv0 - (unsigned int)(t5*16);
            ctile(a0h0,a0h1,a0l0,a0l1, Ah0,Ah1,Al0,Al1, tk0, inv);
            ctile(a1h0,a1h1,a1l0,a1l1, Ah0,Ah1,Al0,Al1, tk1, inv);
            ctile(a2h0,a2h1,a2l0,a2l1, Ah0,Ah1,Al0,Al1, tk2, inv);
            ctile(a3h0,a3h1,a3l0,a3l1, Ah0,Ah1,Al0,Al1, tk3, inv);
        }
        {   // prefetch t5+2 (clamped on last iter; dummy, unused)
            int m = (t5+2 < 32) ? (t5+2) : 0;
            const unsigned short* p = bp + (size_t)m*16*128;
            Ah0 = *(const bf16x8*)(p);
            Ah1 = *(const bf16x8*)(p + 32);
            Al0 = *(const bf16x8*)(p + 64);
            Al1 = *(const bf16x8*)(p + 96);
        }
        {
            unsigned int inv = inv0 - (unsigned int)((t5+1)*16);
            ctile(a0h0,a0h1,a0l0,a0l1, Bh0,Bh1,Bl0,Bl1, tk0, inv);
            ctile(a1h0,a1h1,a1l0,a1l1, Bh0,Bh1,Bl0,Bl1, tk1, inv);
            ctile(a2h0,a2h1,a2l0,a2l1, Bh0,Bh1,Bl0,Bl1, tk2, inv);
            ctile(a3h0,a3h1,a3l0,a3l1, Bh0,Bh1,Bl0,Bl1, tk3, inv);
        }
    }

    #pragma unroll
    for (int m = 1; m < 16; m <<= 1) {
        #pragma unroll
        for (int r=0;r<4;++r) {
            unsigned int o0[5], o1[5], o2[5], o3[5];
            #pragma unroll
            for (int kk=0;kk<5;++kk) {
                o0[kk] = (unsigned int)__shfl_xor((int)tk0[r][kk], m);
                o1[kk] = (unsigned int)__shfl_xor((int)tk1[r][kk], m);
                o2[kk] = (unsigned int)__shfl_xor((int)tk2[r][kk], m);
                o3[kk] = (unsigned int)__shfl_xor((int)tk3[r][kk], m);
            }
            #pragma unroll
            for (int kk=0;kk<5;++kk) {
                ins5k(tk0[r], o0[kk]); ins5k(tk1[r], o1[kk]);
                ins5k(tk2[r], o2[kk]); ins5k(tk3[r], o3[kk]);
            }
        }
    }
    if (ln == 0) {
        int rowb = rg*256 + wave*64 + kh*4;
        #pragma unroll
        for (int r=0;r<4;++r) {
            size_t b0 = (((size_t)b*NN + rowb + r)*8 + cs)*5;
            size_t b1 = (((size_t)b*NN + rowb + 16 + r)*8 + cs)*5;
            size_t b2 = (((size_t)b*NN + rowb + 32 + r)*8 + cs)*5;
            size_t b3 = (((size_t)b*NN + rowb + 48 + r)*8 + cs)*5;
            #pragma unroll
            for (int kk=0;kk<5;++kk) {
                pk[b0+kk] = tk0[r][kk]; pk[b1+kk] = tk1[r][kk];
                pk[b2+kk] = tk2[r][kk]; pk[b3+kk] = tk3[r][kk];
            }
        }
    }
}

// ---------- K2: merged topk(512) | qkv(768) — both zero-LDS, ~128 VGPR ----------
// idx%5<2 -> topk, else qkv: interleaves block types across CUs so qkv VALU/MFMA
// fills topk's load-stall slots (m114 overlap). Unlike r10's failed fusion, the
// paths share the same register/LDS class, so neither degrades the other.
__global__ __launch_bounds__(256, 2) void k_mix(
    const unsigned short* __restrict__ hl, const float* __restrict__ nrm,
    const unsigned short* __restrict__ wsb,
    const float* __restrict__ bk, const float* __restrict__ bq, const float* __restrict__ bv,
    float* __restrict__ qo, float* __restrict__ ko, float* __restrict__ vo,
    unsigned int* __restrict__ pk)
{
    int idx = blockIdx.x;
    int q = idx / 5, m5 = idx % 5;
    if (m5 < 2) topk_body(q*2 + m5, hl, pk);
    else        qkv_body(q*3 + (m5-2), hl, nrm, wsb, bk, bq, bv, qo, ko, vo);
}

// ---------- K4: fused top-5 merge + laplacian(k)·laplacian(v) partial reduction ----------
__global__ __launch_bounds__(256) void k_kv(const float* __restrict__ ko, const float* __restrict__ vo,
                                            const unsigned int* __restrict__ pk, float* __restrict__ part)
{
    int blk = blockIdx.x;                 // bh(16) * chunk(32)
    int chunk = blk & 31, bh = blk >> 5, b = bh >> 2;
    int t = threadIdx.x;
    __shared__ int idxl[128][5];
    __shared__ float red[4][64];
    if (t < 128) {
        int n = chunk*128 + t;
        const uint4* pp = (const uint4*)(pk + ((size_t)b*NN + n)*40);
        unsigned int bk5[5] = {0u,0u,0u,0u,0u};
        #pragma unroll
        for (int e = 0; e < 10; ++e) {
            uint4 v4 = pp[e];
            ins5k(bk5, v4.x); ins5k(bk5, v4.y); ins5k(bk5, v4.z); ins5k(bk5, v4.w);
        }
        #pragma unroll
        for (int kk=0;kk<5;++kk) idxl[t][kk] = 4095 - (int)(bk5[kk] & 0xFFFu);
    }
    __syncthreads();
    int f = t & 63, g = t >> 6;
    const float* kb = ko + (size_t)bh*NN*64;
    const float* vb = vo + (size_t)bh*NN*64;
    float acc = 0.f;
    for (int i2 = 0; i2 < 32; ++i2) {
        int nl = g*32 + i2;
        int n = chunk*128 + nl;
        const int* ip = idxl[nl];
        int j0 = ip[0], j1 = ip[1], j2 = ip[2], j3 = ip[3], j4 = ip[4];
        float lk = kb[(size_t)n*64+f] + kb[(size_t)j0*64+f] + kb[(size_t)j1*64+f]
                 + kb[(size_t)j2*64+f] + kb[(size_t)j3*64+f] + kb[(size_t)j4*64+f];
        float lv = vb[(size_t)n*64+f] + vb[(size_t)j0*64+f] + vb[(size_t)j1*64+f]
                 + vb[(size_t)j2*64+f] + vb[(size_t)j3*64+f] + vb[(size_t)j4*64+f];
        acc += lk*lv;
    }
    red[g][f] = acc;
    __syncthreads();
    if (t < 64) {
        float s2 = red[0][t] + red[1][t] + red[2][t] + red[3][t];
        part[((size_t)bh*64 + t)*32 + chunk] = s2;
    }
}

// ---------- K6: fused kv-scale + (hy·wp) conv + conv1/BN/ReLU + conv2/BN/ReLU ----------
__global__ __launch_bounds__(256) void k_out(
    const float* __restrict__ qo, const float* __restrict__ wp, const float* __restrict__ part,
    const float* __restrict__ bp,
    const float* __restrict__ w1, const float* __restrict__ b1,
    const float* __restrict__ w2, const float* __restrict__ b2,
    const float* __restrict__ g1, const float* __restrict__ be1,
    const float* __restrict__ m1, const float* __restrict__ v1,
    const float* __restrict__ g2, const float* __restrict__ be2,
    const float* __restrict__ m2, const float* __restrict__ v2,
    float* __restrict__ outp)
{
    int b  = blockIdx.x >> 6;
    int n0 = (blockIdx.x & 63)*64;
    __shared__ __align__(16) float qs[256*68];   // q tile [hf][nl]; later t1 [o][nl]
    __shared__ __align__(16) float ws2[256*68];  // wps [hf][o]; later w1s/w2s [c][o]
    __shared__ __align__(16) float t0[64*68];    // conv_p out [o][nl]; later t2
    int t = threadIdx.x;
    {
        int f = t & 63, sub = t >> 6;
        #pragma unroll
        for (int h = 0; h < 4; ++h) {
            const float* qb = qo + (((size_t)(b*4+h))*NN + n0)*64 + f;
            for (int nl = sub; nl < 64; nl += 4)
                qs[(h*64+f)*68 + nl] = qb[(size_t)nl*64];
        }
    }
    {   // kv reduction for hf=t (folded k_wps): ws2[t][o] = wp[o][t] * kv
        const float* pp = part + ((size_t)b*256 + t)*32;
        float s = 0.f;
        #pragma unroll
        for (int c2 = 0; c2 < 32; ++c2) s += pp[c2];
        float kvv = s * (1.f/36.f);
        for (int o = 0; o < 64; ++o)
            ws2[t*68 + o] = wp[(size_t)o*256 + t] * kvv;
    }
    __syncthreads();
    int tr = t >> 4, tc = t & 15;
    float acc[4][4];
    #pragma unroll
    for (int i=0;i<4;++i) {
        float bb = bp[tr*4+i];
        #pragma unroll
        for (int j=0;j<4;++j) acc[i][j] = bb;
    }
    #pragma unroll 8
    for (int hf = 0; hf < 256; ++hf) {
        float4 a4 = *(const float4*)&ws2[hf*68 + tr*4];
        float4 b4 = *(const float4*)&qs[hf*68 + tc*4];
        float av[4]={a4.x,a4.y,a4.z,a4.w}, bvv[4]={b4.x,b4.y,b4.z,b4.w};
        #pragma unroll
        for (int i=0;i<4;++i)
            #pragma unroll
            for (int j=0;j<4;++j)
                acc[i][j] += av[i]*bvv[j];
    }
    #pragma unroll
    for (int i=0;i<4;++i)
        *(float4*)&t0[(tr*4+i)*68 + tc*4] = make_float4(acc[i][0],acc[i][1],acc[i][2],acc[i][3]);
    __syncthreads();
    #pragma unroll
    for (int s = 0; s < 16; ++s) {   // w1 transposed into ws2
        int e = t + 256*s;
        ws2[(e & 63)*68 + (e >> 6)] = w1[e];
    }
    __syncthreads();
    float acc2[4][4];
    #pragma unroll
    for (int i=0;i<4;++i)
        #pragma unroll
        for (int j=0;j<4;++j) acc2[i][j] = 0.f;
    #pragma unroll 8
    for (int c = 0; c < 64; ++c) {
        float4 a4 = *(const float4*)&ws2[c*68 + tr*4];
        float4 b4 = *(const float4*)&t0[c*68 + tc*4];
        float av[4]={a4.x,a4.y,a4.z,a4.w}, bvv[4]={b4.x,b4.y,b4.z,b4.w};
        #pragma unroll
        for (int i=0;i<4;++i)
            #pragma unroll
            for (int j=0;j<4;++j)
                acc2[i][j] += av[i]*bvv[j];
    }
    #pragma unroll
    for (int i=0;i<4;++i) {          // BN1 + ReLU -> t1 (in qs region)
        int o = tr*4+i;
        float sc = g1[o] / sqrtf(v1[o] + 1e-5f);
        float bb = b1[o], mm = m1[o], bt = be1[o];
        float4 r;
        r.x = fmaxf((acc2[i][0]+bb-mm)*sc + bt, 0.f);
        r.y = fmaxf((acc2[i][1]+bb-mm)*sc + bt, 0.f);
        r.z = fmaxf((acc2[i][2]+bb-mm)*sc + bt, 0.f);
        r.w = fmaxf((acc2[i][3]+bb-mm)*sc + bt, 0.f);
        *(float4*)&qs[o*68 + tc*4] = r;
    }
    __syncthreads();
    #pragma unroll
    for (int s = 0; s < 16; ++s) {   // w2 transposed into ws2
        int e = t + 256*s;
        ws2[(e & 63)*68 + (e >> 6)] = w2[e];
    }
    __syncthreads();
    float acc3[4][4];
    #pragma unroll
    for (int i=0;i<4;++i)
        #pragma unroll
        for (int j=0;j<4;++j) acc3[i][j] = 0.f;
    #pragma unroll 8
    for (int c = 0; c < 64; ++c) {
        float4 a4 = *(const float4*)&ws2[c*68 + tr*4];
        float4 b4 = *(const float4*)&qs[c*68 + tc*4];
        float av[4]={a4.x,a4.y,a4.z,a4.w}, bvv[4]={b4.x,b4.y,b4.z,b4.w};
        #pragma unroll
        for (int i=0;i<4;++i)
            #pragma unroll
            for (int j=0;j<4;++j)
                acc3[i][j] += av[i]*bvv[j];
    }
    #pragma unroll
    for (int i=0;i<4;++i) {          // BN2 + ReLU -> t2 (in t0 region)
        int o = tr*4+i;
        float sc = g2[o] / sqrtf(v2[o] + 1e-5f);
        float bb = b2[o], mm = m2[o], bt = be2[o];
        float4 r;
        r.x = fmaxf((acc3[i][0]+bb-mm)*sc + bt, 0.f);
        r.y = fmaxf((acc3[i][1]+bb-mm)*sc + bt, 0.f);
        r.z = fmaxf((acc3[i][2]+bb-mm)*sc + bt, 0.f);
        r.w = fmaxf((acc3[i][3]+bb-mm)*sc + bt, 0.f);
        *(float4*)&t0[o*68 + tc*4] = r;
    }
    __syncthreads();
    float* ob = outp + ((size_t)b*64)*NN + n0;
    #pragma unroll
    for (int s = 0; s < 16; ++s) {
        int e = t + 256*s;
        int o = e >> 6, nl = e & 63;
        ob[(size_t)o*NN + nl] = t0[o*68 + nl];
    }
}

extern "C" void kernel_launch(void* const* d_in, const int* in_sizes, int n_in,
                              void* d_out, int out_size, void* d_ws, size_t ws_size,
                              hipStream_t stream)
{
    (void)in_sizes; (void)n_in; (void)out_size; (void)ws_size;
    const float* x  = (const float*)d_in[0];
    const float* wk = (const float*)d_in[1];
    const float* bk = (const float*)d_in[2];
    const float* wq = (const float*)d_in[3];
    const float* bq = (const float*)d_in[4];
    const float* wv = (const float*)d_in[5];
    const float* bv = (const float*)d_in[6];
    const float* wp = (const float*)d_in[7];
    const float* bp = (const float*)d_in[8];
    const float* w1 = (const float*)d_in[9];
    const float* b1 = (const float*)d_in[10];
    const float* w2 = (const float*)d_in[11];
    const float* b2 = (const float*)d_in[12];
    const float* g1 = (const float*)d_in[13];
    const float* be1= (const float*)d_in[14];
    const float* m1 = (const float*)d_in[15];
    const float* v1 = (const float*)d_in[16];
    const float* g2 = (const float*)d_in[17];
    const float* be2= (const float*)d_in[18];
    const float* m2 = (const float*)d_in[19];
    const float* v2 = (const float*)d_in[20];
    float* out = (float*)d_out;

    float* ws = (float*)d_ws;
    unsigned short* hlb = (unsigned short*)ws;  ws += (size_t)NB*NN*128/2;  // 4MB interleaved hi|lo
    unsigned short* wsb = (unsigned short*)ws;  ws += (size_t)768*128/2;    // 196KB weight split
    float* nrm  = ws;  ws += (size_t)NB*NN;           // 64KB node norms
    float* qbuf = ws;  ws += (size_t)NB*NH*NN*64;     // 16MB
    float* kbuf = ws;  ws += (size_t)NB*NH*NN*64;
    float* vbuf = ws;  ws += (size_t)NB*NH*NN*64;
    float* part = ws;  ws += (size_t)16*64*32;
    unsigned int* pk = (unsigned int*)ws;  ws += (size_t)NB*NN*40;  // 655,360 u32

    k_pre<<<259, 256, 0, stream>>>(x, wk, wq, wv, hlb, nrm, wsb);
    k_mix<<<1280, 256, 0, stream>>>(hlb, nrm, wsb, bk, bq, bv, qbuf, kbuf, vbuf, pk);
    k_kv<<<512, 256, 0, stream>>>(kbuf, vbuf, pk, part);
    k_out<<<256, 256, 0, stream>>>(qbuf, wp, part, bp, w1,b1, w2,b2,
                                   g1,be1,m1,v1, g2,be2,m2,v2, out);
}

// Round 19
// 144.312 us; speedup vs baseline: 1.1129x; 1.1129x over previous
//
#include <hip/hip_runtime.h>
#include <math.h>

#define NB 4
#define NC 64
#define NN 4096
#define NH 4

typedef __attribute__((ext_vector_type(8))) short bf16x8;
typedef __attribute__((ext_vector_type(4))) float f32x4;

// ---------- RNE float -> bf16 bits ----------
__device__ __forceinline__ unsigned int bf16rne(float v) {
    unsigned int u = __float_as_uint(v);
    return (u + 0x7fffu + ((u >> 16) & 1u)) >> 16;
}

// ---------- top-5 insert, depth-2 med3 form ----------
__device__ __forceinline__ void ins5k(unsigned int (&tk)[5], unsigned int key) {
    unsigned int n0 = max(tk[0], key);
    unsigned int n1 = min(tk[0], max(tk[1], key));
    unsigned int n2 = min(tk[1], max(tk[2], key));
    unsigned int n3 = min(tk[2], max(tk[3], key));
    unsigned int n4 = min(tk[3], max(tk[4], key));
    tk[0]=n0; tk[1]=n1; tk[2]=n2; tk[3]=n3; tk[4]=n4;
}

// ---------- split helper: 8 floats -> hi uint4 + lo uint4 ----------
__device__ __forceinline__ void split8(const float* v, uint4& hw4, uint4& lw4) {
    unsigned int hw[4], lw[4];
    #pragma unroll
    for (int p = 0; p < 4; ++p) {
        float v0 = v[p*2], v1 = v[p*2+1];
        unsigned int h0 = bf16rne(v0), h1 = bf16rne(v1);
        float r0 = v0 - __uint_as_float(h0 << 16);
        float r1 = v1 - __uint_as_float(h1 << 16);
        unsigned int l0 = bf16rne(r0), l1 = bf16rne(r1);
        hw[p] = h0 | (h1 << 16);
        lw[p] = l0 | (l1 << 16);
    }
    hw4 = make_uint4(hw[0], hw[1], hw[2], hw[3]);
    lw4 = make_uint4(lw[0], lw[1], lw[2], lw[3]);
}

// ---------- K0: xsplit (4 waves/64-node group) + nrm + weight split ----------
__global__ __launch_bounds__(256) void k_pre(
    const float* __restrict__ x,
    const float* __restrict__ wk, const float* __restrict__ wq, const float* __restrict__ wv,
    unsigned short* __restrict__ hl, float* __restrict__ nrm,
    unsigned short* __restrict__ wsb)
{
    __shared__ float redn[4][64];
    int blk = blockIdx.x;
    int t = threadIdx.x;
    if (blk >= 256) {   // ---- weight split ----
        int r = (blk - 256)*256 + t;     // 0..767
        int mat = r >> 8, oc = r & 255;
        const float* wsrc = (mat==0) ? wk : ((mat==1) ? wq : wv);
        float wrow[64];
        #pragma unroll
        for (int g = 0; g < 16; ++g)
            *(float4*)&wrow[g*4] = *(const float4*)(wsrc + (size_t)oc*64 + g*4);
        unsigned short* wo = wsb + (size_t)r*128;
        #pragma unroll
        for (int g = 0; g < 8; ++g) {
            uint4 hw4, lw4;
            split8(&wrow[g*8], hw4, lw4);
            *(uint4*)(wo + g*8)      = hw4;
            *(uint4*)(wo + 64 + g*8) = lw4;
        }
        return;
    }
    // ---- xsplit ----
    int lane = t & 63, g = t >> 6;
    int node = blk*64 + lane;                    // flat (b,n); batch-aligned blocks
    const float* xb = x + ((size_t)(node >> 12))*NC*NN + (node & (NN-1));
    float vals[16];
    float ss = 0.f;
    #pragma unroll
    for (int i = 0; i < 16; ++i) {
        vals[i] = xb[(size_t)(g*16 + i)*NN];
        ss += vals[i]*vals[i];
    }
    redn[g][lane] = ss;
    __syncthreads();
    float st = redn[0][lane] + redn[1][lane] + redn[2][lane] + redn[3][lane];
    float rn = 1.f / fmaxf(sqrtf(st), 1e-12f);
    if (g == 0) nrm[node] = sqrtf(st);
    float nv[16];
    #pragma unroll
    for (int i = 0; i < 16; ++i) nv[i] = vals[i] * rn;
    unsigned short* ho = hl + (size_t)node*128 + g*16;
    #pragma unroll
    for (int gg = 0; gg < 2; ++gg) {
        uint4 hw4, lw4;
        split8(&nv[gg*8], hw4, lw4);
        *(uint4*)(ho + gg*8)      = hw4;
        *(uint4*)(ho + 64 + gg*8) = lw4;
    }
}

// ---------- K2: MFMA q/k/v projections from hlb (W·x = nrm·(W·xn)) ----------
// Grid = nt(64) x {mat(3),b(4)} = 768; 4 waves/block, wave = head h. Zero LDS.
__global__ __launch_bounds__(256, 2) void k_qkv(
    const unsigned short* __restrict__ hl, const float* __restrict__ nrm,
    const unsigned short* __restrict__ wsb,
    const float* __restrict__ bk, const float* __restrict__ bq, const float* __restrict__ bv,
    float* __restrict__ qo, float* __restrict__ ko, float* __restrict__ vo)
{
    int blk = blockIdx.x;
    int nt  = blk & 63;
    int rem = blk >> 6;          // 0..11
    int mat = rem % 3, b = rem / 3;
    const float* bias = (mat==0) ? bk : ((mat==1) ? bq : bv);
    float* outp       = (mat==0) ? ko : ((mat==1) ? qo : vo);
    int t = threadIdx.x, lane = t & 63, h = t >> 6;
    int ln = lane & 15, kh = lane >> 4;

    bf16x8 ah0[4], ah1[4], al0[4], al1[4];
    const unsigned short* wb2 = wsb + ((size_t)(mat*256 + h*64 + ln))*128 + kh*8;
    #pragma unroll
    for (int s = 0; s < 4; ++s) {
        const unsigned short* p = wb2 + (size_t)s*16*128;
        ah0[s] = *(const bf16x8*)(p);
        ah1[s] = *(const bf16x8*)(p + 32);
        al0[s] = *(const bf16x8*)(p + 64);
        al1[s] = *(const bf16x8*)(p + 96);
    }
    float4 bj[4];
    #pragma unroll
    for (int s = 0; s < 4; ++s) bj[s] = *(const float4*)(bias + h*64 + s*16 + kh*4);

    int n0base = nt*64;
    const unsigned short* xb2 = hl + ((size_t)b*NN + n0base + ln)*128 + kh*8;
    #pragma unroll
    for (int j = 0; j < 4; ++j) {
        const unsigned short* p = xb2 + (size_t)j*16*128;
        bf16x8 bh0 = *(const bf16x8*)(p);
        bf16x8 bh1 = *(const bf16x8*)(p + 32);
        bf16x8 bl0 = *(const bf16x8*)(p + 64);
        bf16x8 bl1 = *(const bf16x8*)(p + 96);
        int n = n0base + j*16 + ln;
        float sc = nrm[(size_t)b*NN + n];
        f32x4 av[4];
        #pragma unroll
        for (int s = 0; s < 4; ++s) {
            f32x4 acc = {0.f, 0.f, 0.f, 0.f};
            acc = __builtin_amdgcn_mfma_f32_16x16x32_bf16(ah0[s], bh0, acc, 0,0,0);
            acc = __builtin_amdgcn_mfma_f32_16x16x32_bf16(ah1[s], bh1, acc, 0,0,0);
            acc = __builtin_amdgcn_mfma_f32_16x16x32_bf16(al0[s], bh0, acc, 0,0,0);
            acc = __builtin_amdgcn_mfma_f32_16x16x32_bf16(al1[s], bh1, acc, 0,0,0);
            acc = __builtin_amdgcn_mfma_f32_16x16x32_bf16(ah0[s], bl0, acc, 0,0,0);
            acc = __builtin_amdgcn_mfma_f32_16x16x32_bf16(ah1[s], bl1, acc, 0,0,0);
            av[s][0] = acc[0]*sc + bj[s].x;
            av[s][1] = acc[1]*sc + bj[s].y;
            av[s][2] = acc[2]*sc + bj[s].z;
            av[s][3] = acc[3]*sc + bj[s].w;
        }
        float* ob = outp + (((size_t)(b*NH + h))*NN + n)*64 + kh*4;
        if (mat != 2) {
            float ss = 0.f;
            #pragma unroll
            for (int s = 0; s < 4; ++s)
                ss += av[s][0]*av[s][0] + av[s][1]*av[s][1]
                    + av[s][2]*av[s][2] + av[s][3]*av[s][3];
            ss += __shfl_xor(ss, 16);
            ss += __shfl_xor(ss, 32);
            float rn = 1.f / fmaxf(sqrtf(ss), 1e-12f);
            #pragma unroll
            for (int s = 0; s < 4; ++s)
                *(float4*)(ob + s*16) = make_float4(av[s][0]*rn, av[s][1]*rn,
                                                    av[s][2]*rn, av[s][3]*rn);
        } else {
            #pragma unroll
            for (int s = 0; s < 4; ++s)
                *(float4*)(ob + s*16) = make_float4(av[s][0], av[s][1],
                                                    av[s][2], av[s][3]);
        }
    }
}

// ---------- K3: MFMA split-bf16 sim + packed-key top-5 (r15/r16/r17, unchanged) ----------
__device__ __forceinline__ void ctile(const bf16x8& ah0, const bf16x8& ah1,
                                      const bf16x8& al0, const bf16x8& al1,
                                      const bf16x8& bh0, const bf16x8& bh1,
                                      const bf16x8& bl0, const bf16x8& bl1,
                                      unsigned int (&tk)[4][5], unsigned int inv)
{
    f32x4 accP = {2.0f, 2.0f, 2.0f, 2.0f};   // pack bias pre-seeded
    f32x4 accQ = {0.f, 0.f, 0.f, 0.f};
    f32x4 accR = {0.f, 0.f, 0.f, 0.f};
    accP = __builtin_amdgcn_mfma_f32_16x16x32_bf16(ah0, bh0, accP, 0,0,0);
    accQ = __builtin_amdgcn_mfma_f32_16x16x32_bf16(al0, bh0, accQ, 0,0,0);
    accR = __builtin_amdgcn_mfma_f32_16x16x32_bf16(ah0, bl0, accR, 0,0,0);
    accP = __builtin_amdgcn_mfma_f32_16x16x32_bf16(ah1, bh1, accP, 0,0,0);
    accQ = __builtin_amdgcn_mfma_f32_16x16x32_bf16(al1, bh1, accQ, 0,0,0);
    accR = __builtin_amdgcn_mfma_f32_16x16x32_bf16(ah1, bl1, accR, 0,0,0);
    #pragma unroll
    for (int r = 0; r < 4; ++r) {
        float v = (accP[r] + accQ[r]) + accR[r];
        unsigned int key = (__float_as_uint(v) & 0xFFFFF000u) | inv;
        ins5k(tk[r], key);
    }
}

__global__ __launch_bounds__(256, 2)
void k_topk(const unsigned short* __restrict__ hl, unsigned int* __restrict__ pk)
{
    int blk = blockIdx.x;
    int cs = blk & 7;
    int rg = (blk >> 3) & 15;
    int b  = blk >> 7;
    int t = threadIdx.x, lane = t & 63, wave = t >> 6;
    int ln = lane & 15, kh = lane >> 4;
    const unsigned short* hb = hl + (size_t)b*NN*128;

    const unsigned short* ap0 = hb + (size_t)(rg*256 + wave*64 + ln)*128 + kh*8;
    bf16x8 a0h0 = *(const bf16x8*)(ap0);
    bf16x8 a0h1 = *(const bf16x8*)(ap0 + 32);
    bf16x8 a0l0 = *(const bf16x8*)(ap0 + 64);
    bf16x8 a0l1 = *(const bf16x8*)(ap0 + 96);
    const unsigned short* ap1 = ap0 + 16*128;
    bf16x8 a1h0 = *(const bf16x8*)(ap1);
    bf16x8 a1h1 = *(const bf16x8*)(ap1 + 32);
    bf16x8 a1l0 = *(const bf16x8*)(ap1 + 64);
    bf16x8 a1l1 = *(const bf16x8*)(ap1 + 96);
    const unsigned short* ap2 = ap0 + 32*128;
    bf16x8 a2h0 = *(const bf16x8*)(ap2);
    bf16x8 a2h1 = *(const bf16x8*)(ap2 + 32);
    bf16x8 a2l0 = *(const bf16x8*)(ap2 + 64);
    bf16x8 a2l1 = *(const bf16x8*)(ap2 + 96);
    const unsigned short* ap3 = ap0 + 48*128;
    bf16x8 a3h0 = *(const bf16x8*)(ap3);
    bf16x8 a3h1 = *(const bf16x8*)(ap3 + 32);
    bf16x8 a3l0 = *(const bf16x8*)(ap3 + 64);
    bf16x8 a3l1 = *(const bf16x8*)(ap3 + 96);

    unsigned int tk0[4][5], tk1[4][5], tk2[4][5], tk3[4][5];
    #pragma unroll
    for (int r=0;r<4;++r)
        #pragma unroll
        for (int kk=0;kk<5;++kk) { tk0[r][kk]=0u; tk1[r][kk]=0u; tk2[r][kk]=0u; tk3[r][kk]=0u; }

    int colbase = cs*512;
    unsigned int inv0 = 4095u - (unsigned int)(colbase + ln);

    const unsigned short* bp = hb + (size_t)(colbase + ln)*128 + kh*8;
    bf16x8 Ah0 = *(const bf16x8*)(bp);
    bf16x8 Ah1 = *(const bf16x8*)(bp + 32);
    bf16x8 Al0 = *(const bf16x8*)(bp + 64);
    bf16x8 Al1 = *(const bf16x8*)(bp + 96);
    bf16x8 Bh0, Bh1, Bl0, Bl1;

    for (int t5 = 0; t5 < 32; t5 += 2) {
        {   // prefetch t5+1
            const unsigned short* p = bp + (size_t)(t5+1)*16*128;
            Bh0 = *(const bf16x8*)(p);
            Bh1 = *(const bf16x8*)(p + 32);
            Bl0 = *(const bf16x8*)(p + 64);
            Bl1 = *(const bf16x8*)(p + 96);
        }
        {
            unsigned int inv = inv0 - (unsigned int)(t5*16);
            ctile(a0h0,a0h1,a0l0,a0l1, Ah0,Ah1,Al0,Al1, tk0, inv);
            ctile(a1h0,a1h1,a1l0,a1l1, Ah0,Ah1,Al0,Al1, tk1, inv);
            ctile(a2h0,a2h1,a2l0,a2l1, Ah0,Ah1,Al0,Al1, tk2, inv);
            ctile(a3h0,a3h1,a3l0,a3l1, Ah0,Ah1,Al0,Al1, tk3, inv);
        }
        {   // prefetch t5+2 (clamped on last iter; dummy, unused)
            int m = (t5+2 < 32) ? (t5+2) : 0;
            const unsigned short* p = bp + (size_t)m*16*128;
            Ah0 = *(const bf16x8*)(p);
            Ah1 = *(const bf16x8*)(p + 32);
            Al0 = *(const bf16x8*)(p + 64);
            Al1 = *(const bf16x8*)(p + 96);
        }
        {
            unsigned int inv = inv0 - (unsigned int)((t5+1)*16);
            ctile(a0h0,a0h1,a0l0,a0l1, Bh0,Bh1,Bl0,Bl1, tk0, inv);
            ctile(a1h0,a1h1,a1l0,a1l1, Bh0,Bh1,Bl0,Bl1, tk1, inv);
            ctile(a2h0,a2h1,a2l0,a2l1, Bh0,Bh1,Bl0,Bl1, tk2, inv);
            ctile(a3h0,a3h1,a3l0,a3l1, Bh0,Bh1,Bl0,Bl1, tk3, inv);
        }
    }

    #pragma unroll
    for (int m = 1; m < 16; m <<= 1) {
        #pragma unroll
        for (int r=0;r<4;++r) {
            unsigned int o0[5], o1[5], o2[5], o3[5];
            #pragma unroll
            for (int kk=0;kk<5;++kk) {
                o0[kk] = (unsigned int)__shfl_xor((int)tk0[r][kk], m);
                o1[kk] = (unsigned int)__shfl_xor((int)tk1[r][kk], m);
                o2[kk] = (unsigned int)__shfl_xor((int)tk2[r][kk], m);
                o3[kk] = (unsigned int)__shfl_xor((int)tk3[r][kk], m);
            }
            #pragma unroll
            for (int kk=0;kk<5;++kk) {
                ins5k(tk0[r], o0[kk]); ins5k(tk1[r], o1[kk]);
                ins5k(tk2[r], o2[kk]); ins5k(tk3[r], o3[kk]);
            }
        }
    }
    if (ln == 0) {
        int rowb = rg*256 + wave*64 + kh*4;
        #pragma unroll
        for (int r=0;r<4;++r) {
            size_t b0 = (((size_t)b*NN + rowb + r)*8 + cs)*5;
            size_t b1 = (((size_t)b*NN + rowb + 16 + r)*8 + cs)*5;
            size_t b2 = (((size_t)b*NN + rowb + 32 + r)*8 + cs)*5;
            size_t b3 = (((size_t)b*NN + rowb + 48 + r)*8 + cs)*5;
            #pragma unroll
            for (int kk=0;kk<5;++kk) {
                pk[b0+kk] = tk0[r][kk]; pk[b1+kk] = tk1[r][kk];
                pk[b2+kk] = tk2[r][kk]; pk[b3+kk] = tk3[r][kk];
            }
        }
    }
}

// ---------- K4: fused top-5 merge + laplacian(k)·laplacian(v) partial reduction ----------
__global__ __launch_bounds__(256) void k_kv(const float* __restrict__ ko, const float* __restrict__ vo,
                                            const unsigned int* __restrict__ pk, float* __restrict__ part)
{
    int blk = blockIdx.x;                 // bh(16) * chunk(32)
    int chunk = blk & 31, bh = blk >> 5, b = bh >> 2;
    int t = threadIdx.x;
    __shared__ int idxl[128][5];
    __shared__ float red[4][64];
    if (t < 128) {
        int n = chunk*128 + t;
        const uint4* pp = (const uint4*)(pk + ((size_t)b*NN + n)*40);
        unsigned int bk5[5] = {0u,0u,0u,0u,0u};
        #pragma unroll
        for (int e = 0; e < 10; ++e) {
            uint4 v4 = pp[e];
            ins5k(bk5, v4.x); ins5k(bk5, v4.y); ins5k(bk5, v4.z); ins5k(bk5, v4.w);
        }
        #pragma unroll
        for (int kk=0;kk<5;++kk) idxl[t][kk] = 4095 - (int)(bk5[kk] & 0xFFFu);
    }
    __syncthreads();
    int f = t & 63, g = t >> 6;
    const float* kb = ko + (size_t)bh*NN*64;
    const float* vb = vo + (size_t)bh*NN*64;
    float acc = 0.f;
    for (int i2 = 0; i2 < 32; ++i2) {
        int nl = g*32 + i2;
        int n = chunk*128 + nl;
        const int* ip = idxl[nl];
        int j0 = ip[0], j1 = ip[1], j2 = ip[2], j3 = ip[3], j4 = ip[4];
        float lk = kb[(size_t)n*64+f] + kb[(size_t)j0*64+f] + kb[(size_t)j1*64+f]
                 + kb[(size_t)j2*64+f] + kb[(size_t)j3*64+f] + kb[(size_t)j4*64+f];
        float lv = vb[(size_t)n*64+f] + vb[(size_t)j0*64+f] + vb[(size_t)j1*64+f]
                 + vb[(size_t)j2*64+f] + vb[(size_t)j3*64+f] + vb[(size_t)j4*64+f];
        acc += lk*lv;
    }
    red[g][f] = acc;
    __syncthreads();
    if (t < 64) {
        float s2 = red[0][t] + red[1][t] + red[2][t] + red[3][t];
        part[((size_t)bh*64 + t)*32 + chunk] = s2;
    }
}

// ---------- K6: fused kv-scale + (hy·wp) conv + conv1/BN/ReLU + conv2/BN/ReLU ----------
__global__ __launch_bounds__(256) void k_out(
    const float* __restrict__ qo, const float* __restrict__ wp, const float* __restrict__ part,
    const float* __restrict__ bp,
    const float* __restrict__ w1, const float* __restrict__ b1,
    const float* __restrict__ w2, const float* __restrict__ b2,
    const float* __restrict__ g1, const float* __restrict__ be1,
    const float* __restrict__ m1, const float* __restrict__ v1,
    const float* __restrict__ g2, const float* __restrict__ be2,
    const float* __restrict__ m2, const float* __restrict__ v2,
    float* __restrict__ outp)
{
    int b  = blockIdx.x >> 6;
    int n0 = (blockIdx.x & 63)*64;
    __shared__ __align__(16) float qs[256*68];   // q tile [hf][nl]; later t1 [o][nl]
    __shared__ __align__(16) float ws2[256*68];  // wps [hf][o]; later w1s/w2s [c][o]
    __shared__ __align__(16) float t0[64*68];    // conv_p out [o][nl]; later t2
    int t = threadIdx.x;
    {
        int f = t & 63, sub = t >> 6;
        #pragma unroll
        for (int h = 0; h < 4; ++h) {
            const float* qb = qo + (((size_t)(b*4+h))*NN + n0)*64 + f;
            for (int nl = sub; nl < 64; nl += 4)
                qs[(h*64+f)*68 + nl] = qb[(size_t)nl*64];
        }
    }
    {   // kv reduction for hf=t (folded k_wps): ws2[t][o] = wp[o][t] * kv
        const float* pp = part + ((size_t)b*256 + t)*32;
        float s = 0.f;
        #pragma unroll
        for (int c2 = 0; c2 < 32; ++c2) s += pp[c2];
        float kvv = s * (1.f/36.f);
        for (int o = 0; o < 64; ++o)
            ws2[t*68 + o] = wp[(size_t)o*256 + t] * kvv;
    }
    __syncthreads();
    int tr = t >> 4, tc = t & 15;
    float acc[4][4];
    #pragma unroll
    for (int i=0;i<4;++i) {
        float bb = bp[tr*4+i];
        #pragma unroll
        for (int j=0;j<4;++j) acc[i][j] = bb;
    }
    #pragma unroll 8
    for (int hf = 0; hf < 256; ++hf) {
        float4 a4 = *(const float4*)&ws2[hf*68 + tr*4];
        float4 b4 = *(const float4*)&qs[hf*68 + tc*4];
        float av[4]={a4.x,a4.y,a4.z,a4.w}, bvv[4]={b4.x,b4.y,b4.z,b4.w};
        #pragma unroll
        for (int i=0;i<4;++i)
            #pragma unroll
            for (int j=0;j<4;++j)
                acc[i][j] += av[i]*bvv[j];
    }
    #pragma unroll
    for (int i=0;i<4;++i)
        *(float4*)&t0[(tr*4+i)*68 + tc*4] = make_float4(acc[i][0],acc[i][1],acc[i][2],acc[i][3]);
    __syncthreads();
    #pragma unroll
    for (int s = 0; s < 16; ++s) {   // w1 transposed into ws2
        int e = t + 256*s;
        ws2[(e & 63)*68 + (e >> 6)] = w1[e];
    }
    __syncthreads();
    float acc2[4][4];
    #pragma unroll
    for (int i=0;i<4;++i)
        #pragma unroll
        for (int j=0;j<4;++j) acc2[i][j] = 0.f;
    #pragma unroll 8
    for (int c = 0; c < 64; ++c) {
        float4 a4 = *(const float4*)&ws2[c*68 + tr*4];
        float4 b4 = *(const float4*)&t0[c*68 + tc*4];
        float av[4]={a4.x,a4.y,a4.z,a4.w}, bvv[4]={b4.x,b4.y,b4.z,b4.w};
        #pragma unroll
        for (int i=0;i<4;++i)
            #pragma unroll
            for (int j=0;j<4;++j)
                acc2[i][j] += av[i]*bvv[j];
    }
    #pragma unroll
    for (int i=0;i<4;++i) {          // BN1 + ReLU -> t1 (in qs region)
        int o = tr*4+i;
        float sc = g1[o] / sqrtf(v1[o] + 1e-5f);
        float bb = b1[o], mm = m1[o], bt = be1[o];
        float4 r;
        r.x = fmaxf((acc2[i][0]+bb-mm)*sc + bt, 0.f);
        r.y = fmaxf((acc2[i][1]+bb-mm)*sc + bt, 0.f);
        r.z = fmaxf((acc2[i][2]+bb-mm)*sc + bt, 0.f);
        r.w = fmaxf((acc2[i][3]+bb-mm)*sc + bt, 0.f);
        *(float4*)&qs[o*68 + tc*4] = r;
    }
    __syncthreads();
    #pragma unroll
    for (int s = 0; s < 16; ++s) {   // w2 transposed into ws2
        int e = t + 256*s;
        ws2[(e & 63)*68 + (e >> 6)] = w2[e];
    }
    __syncthreads();
    float acc3[4][4];
    #pragma unroll
    for (int i=0;i<4;++i)
        #pragma unroll
        for (int j=0;j<4;++j) acc3[i][j] = 0.f;
    #pragma unroll 8
    for (int c = 0; c < 64; ++c) {
        float4 a4 = *(const float4*)&ws2[c*68 + tr*4];
        float4 b4 = *(const float4*)&qs[c*68 + tc*4];
        float av[4]={a4.x,a4.y,a4.z,a4.w}, bvv[4]={b4.x,b4.y,b4.z,b4.w};
        #pragma unroll
        for (int i=0;i<4;++i)
            #pragma unroll
            for (int j=0;j<4;++j)
                acc3[i][j] += av[i]*bvv[j];
    }
    #pragma unroll
    for (int i=0;i<4;++i) {          // BN2 + ReLU -> t2 (in t0 region)
        int o = tr*4+i;
        float sc = g2[o] / sqrtf(v2[o] + 1e-5f);
        float bb = b2[o], mm = m2[o], bt = be2[o];
        float4 r;
        r.x = fmaxf((acc3[i][0]+bb-mm)*sc + bt, 0.f);
        r.y = fmaxf((acc3[i][1]+bb-mm)*sc + bt, 0.f);
        r.z = fmaxf((acc3[i][2]+bb-mm)*sc + bt, 0.f);
        r.w = fmaxf((acc3[i][3]+bb-mm)*sc + bt, 0.f);
        *(float4*)&t0[o*68 + tc*4] = r;
    }
    __syncthreads();
    float* ob = outp + ((size_t)b*64)*NN + n0;
    #pragma unroll
    for (int s = 0; s < 16; ++s) {
        int e = t + 256*s;
        int o = e >> 6, nl = e & 63;
        ob[(size_t)o*NN + nl] = t0[o*68 + nl];
    }
}

extern "C" void kernel_launch(void* const* d_in, const int* in_sizes, int n_in,
                              void* d_out, int out_size, void* d_ws, size_t ws_size,
                              hipStream_t stream)
{
    (void)in_sizes; (void)n_in; (void)out_size; (void)ws_size;
    const float* x  = (const float*)d_in[0];
    const float* wk = (const float*)d_in[1];
    const float* bk = (const float*)d_in[2];
    const float* wq = (const float*)d_in[3];
    const float* bq = (const float*)d_in[4];
    const float* wv = (const float*)d_in[5];
    const float* bv = (const float*)d_in[6];
    const float* wp = (const float*)d_in[7];
    const float* bp = (const float*)d_in[8];
    const float* w1 = (const float*)d_in[9];
    const float* b1 = (const float*)d_in[10];
    const float* w2 = (const float*)d_in[11];
    const float* b2 = (const float*)d_in[12];
    const float* g1 = (const float*)d_in[13];
    const float* be1= (const float*)d_in[14];
    const float* m1 = (const float*)d_in[15];
    const float* v1 = (const float*)d_in[16];
    const float* g2 = (const float*)d_in[17];
    const float* be2= (const float*)d_in[18];
    const float* m2 = (const float*)d_in[19];
    const float* v2 = (const float*)d_in[20];
    float* out = (float*)d_out;

    float* ws = (float*)d_ws;
    unsigned short* hlb = (unsigned short*)ws;  ws += (size_t)NB*NN*128/2;  // 4MB interleaved hi|lo
    unsigned short* wsb = (unsigned short*)ws;  ws += (size_t)768*128/2;    // 196KB weight split
    float* nrm  = ws;  ws += (size_t)NB*NN;           // 64KB node norms
    float* qbuf = ws;  ws += (size_t)NB*NH*NN*64;     // 16MB
    float* kbuf = ws;  ws += (size_t)NB*NH*NN*64;
    float* vbuf = ws;  ws += (size_t)NB*NH*NN*64;
    float* part = ws;  ws += (size_t)16*64*32;
    unsigned int* pk = (unsigned int*)ws;  ws += (size_t)NB*NN*40;  // 655,360 u32

    k_pre<<<259, 256, 0, stream>>>(x, wk, wq, wv, hlb, nrm, wsb);
    k_qkv<<<768, 256, 0, stream>>>(hlb, nrm, wsb, bk, bq, bv, qbuf, kbuf, vbuf);
    k_topk<<<512, 256, 0, stream>>>(hlb, pk);
    k_kv<<<512, 256, 0, stream>>>(kbuf, vbuf, pk, part);
    k_out<<<256, 256, 0, stream>>>(qbuf, wp, part, bp, w1,b1, w2,b2,
                                   g1,be1,m1,v1, g2,be2,m2,v2, out);
}

// Round 20
// 138.584 us; speedup vs baseline: 1.1589x; 1.0413x over previous
//
#include <hip/hip_runtime.h>
#include <math.h>

#define NB 4
#define NC 64
#define NN 4096
#define NH 4

typedef __attribute__((ext_vector_type(8))) short bf16x8;
typedef __attribute__((ext_vector_type(4))) float f32x4;

// ---------- RNE float -> bf16 bits ----------
__device__ __forceinline__ unsigned int bf16rne(float v) {
    unsigned int u = __float_as_uint(v);
    return (u + 0x7fffu + ((u >> 16) & 1u)) >> 16;
}

// ---------- top-5 insert, depth-2 med3 form ----------
__device__ __forceinline__ void ins5k(unsigned int (&tk)[5], unsigned int key) {
    unsigned int n0 = max(tk[0], key);
    unsigned int n1 = min(tk[0], max(tk[1], key));
    unsigned int n2 = min(tk[1], max(tk[2], key));
    unsigned int n3 = min(tk[2], max(tk[3], key));
    unsigned int n4 = min(tk[3], max(tk[4], key));
    tk[0]=n0; tk[1]=n1; tk[2]=n2; tk[3]=n3; tk[4]=n4;
}

// ---------- split helper: 8 floats -> hi uint4 + lo uint4 ----------
__device__ __forceinline__ void split8(const float* v, uint4& hw4, uint4& lw4) {
    unsigned int hw[4], lw[4];
    #pragma unroll
    for (int p = 0; p < 4; ++p) {
        float v0 = v[p*2], v1 = v[p*2+1];
        unsigned int h0 = bf16rne(v0), h1 = bf16rne(v1);
        float r0 = v0 - __uint_as_float(h0 << 16);
        float r1 = v1 - __uint_as_float(h1 << 16);
        unsigned int l0 = bf16rne(r0), l1 = bf16rne(r1);
        hw[p] = h0 | (h1 << 16);
        lw[p] = l0 | (l1 << 16);
    }
    hw4 = make_uint4(hw[0], hw[1], hw[2], hw[3]);
    lw4 = make_uint4(lw[0], lw[1], lw[2], lw[3]);
}

// ---------- K0: xsplit (4 waves/64-node group) + nrm + weight split ----------
__global__ __launch_bounds__(256) void k_pre(
    const float* __restrict__ x,
    const float* __restrict__ wk, const float* __restrict__ wq, const float* __restrict__ wv,
    unsigned short* __restrict__ hl, float* __restrict__ nrm,
    unsigned short* __restrict__ wsb)
{
    __shared__ float redn[4][64];
    int blk = blockIdx.x;
    int t = threadIdx.x;
    if (blk >= 256) {   // ---- weight split ----
        int r = (blk - 256)*256 + t;     // 0..767
        int mat = r >> 8, oc = r & 255;
        const float* wsrc = (mat==0) ? wk : ((mat==1) ? wq : wv);
        float wrow[64];
        #pragma unroll
        for (int g = 0; g < 16; ++g)
            *(float4*)&wrow[g*4] = *(const float4*)(wsrc + (size_t)oc*64 + g*4);
        unsigned short* wo = wsb + (size_t)r*128;
        #pragma unroll
        for (int g = 0; g < 8; ++g) {
            uint4 hw4, lw4;
            split8(&wrow[g*8], hw4, lw4);
            *(uint4*)(wo + g*8)      = hw4;
            *(uint4*)(wo + 64 + g*8) = lw4;
        }
        return;
    }
    // ---- xsplit ----
    int lane = t & 63, g = t >> 6;
    int node = blk*64 + lane;                    // flat (b,n); batch-aligned blocks
    const float* xb = x + ((size_t)(node >> 12))*NC*NN + (node & (NN-1));
    float vals[16];
    float ss = 0.f;
    #pragma unroll
    for (int i = 0; i < 16; ++i) {
        vals[i] = xb[(size_t)(g*16 + i)*NN];
        ss += vals[i]*vals[i];
    }
    redn[g][lane] = ss;
    __syncthreads();
    float st = redn[0][lane] + redn[1][lane] + redn[2][lane] + redn[3][lane];
    float rn = 1.f / fmaxf(sqrtf(st), 1e-12f);
    if (g == 0) nrm[node] = sqrtf(st);
    float nv[16];
    #pragma unroll
    for (int i = 0; i < 16; ++i) nv[i] = vals[i] * rn;
    unsigned short* ho = hl + (size_t)node*128 + g*16;
    #pragma unroll
    for (int gg = 0; gg < 2; ++gg) {
        uint4 hw4, lw4;
        split8(&nv[gg*8], hw4, lw4);
        *(uint4*)(ho + gg*8)      = hw4;
        *(uint4*)(ho + 64 + gg*8) = lw4;
    }
}

// ---------- K2: MFMA q/k/v projections from hlb (W·x = nrm·(W·xn)) ----------
__global__ __launch_bounds__(256, 2) void k_qkv(
    const unsigned short* __restrict__ hl, const float* __restrict__ nrm,
    const unsigned short* __restrict__ wsb,
    const float* __restrict__ bk, const float* __restrict__ bq, const float* __restrict__ bv,
    float* __restrict__ qo, float* __restrict__ ko, float* __restrict__ vo)
{
    int blk = blockIdx.x;
    int nt  = blk & 63;
    int rem = blk >> 6;          // 0..11
    int mat = rem % 3, b = rem / 3;
    const float* bias = (mat==0) ? bk : ((mat==1) ? bq : bv);
    float* outp       = (mat==0) ? ko : ((mat==1) ? qo : vo);
    int t = threadIdx.x, lane = t & 63, h = t >> 6;
    int ln = lane & 15, kh = lane >> 4;

    bf16x8 ah0[4], ah1[4], al0[4], al1[4];
    const unsigned short* wb2 = wsb + ((size_t)(mat*256 + h*64 + ln))*128 + kh*8;
    #pragma unroll
    for (int s = 0; s < 4; ++s) {
        const unsigned short* p = wb2 + (size_t)s*16*128;
        ah0[s] = *(const bf16x8*)(p);
        ah1[s] = *(const bf16x8*)(p + 32);
        al0[s] = *(const bf16x8*)(p + 64);
        al1[s] = *(const bf16x8*)(p + 96);
    }
    float4 bj[4];
    #pragma unroll
    for (int s = 0; s < 4; ++s) bj[s] = *(const float4*)(bias + h*64 + s*16 + kh*4);

    int n0base = nt*64;
    const unsigned short* xb2 = hl + ((size_t)b*NN + n0base + ln)*128 + kh*8;
    #pragma unroll
    for (int j = 0; j < 4; ++j) {
        const unsigned short* p = xb2 + (size_t)j*16*128;
        bf16x8 bh0 = *(const bf16x8*)(p);
        bf16x8 bh1 = *(const bf16x8*)(p + 32);
        bf16x8 bl0 = *(const bf16x8*)(p + 64);
        bf16x8 bl1 = *(const bf16x8*)(p + 96);
        int n = n0base + j*16 + ln;
        float sc = nrm[(size_t)b*NN + n];
        f32x4 av[4];
        #pragma unroll
        for (int s = 0; s < 4; ++s) {
            f32x4 acc = {0.f, 0.f, 0.f, 0.f};
            acc = __builtin_amdgcn_mfma_f32_16x16x32_bf16(ah0[s], bh0, acc, 0,0,0);
            acc = __builtin_amdgcn_mfma_f32_16x16x32_bf16(ah1[s], bh1, acc, 0,0,0);
            acc = __builtin_amdgcn_mfma_f32_16x16x32_bf16(al0[s], bh0, acc, 0,0,0);
            acc = __builtin_amdgcn_mfma_f32_16x16x32_bf16(al1[s], bh1, acc, 0,0,0);
            acc = __builtin_amdgcn_mfma_f32_16x16x32_bf16(ah0[s], bl0, acc, 0,0,0);
            acc = __builtin_amdgcn_mfma_f32_16x16x32_bf16(ah1[s], bl1, acc, 0,0,0);
            av[s][0] = acc[0]*sc + bj[s].x;
            av[s][1] = acc[1]*sc + bj[s].y;
            av[s][2] = acc[2]*sc + bj[s].z;
            av[s][3] = acc[3]*sc + bj[s].w;
        }
        float* ob = outp + (((size_t)(b*NH + h))*NN + n)*64 + kh*4;
        if (mat != 2) {
            float ss = 0.f;
            #pragma unroll
            for (int s = 0; s < 4; ++s)
                ss += av[s][0]*av[s][0] + av[s][1]*av[s][1]
                    + av[s][2]*av[s][2] + av[s][3]*av[s][3];
            ss += __shfl_xor(ss, 16);
            ss += __shfl_xor(ss, 32);
            float rn = 1.f / fmaxf(sqrtf(ss), 1e-12f);
            #pragma unroll
            for (int s = 0; s < 4; ++s)
                *(float4*)(ob + s*16) = make_float4(av[s][0]*rn, av[s][1]*rn,
                                                    av[s][2]*rn, av[s][3]*rn);
        } else {
            #pragma unroll
            for (int s = 0; s < 4; ++s)
                *(float4*)(ob + s*16) = make_float4(av[s][0], av[s][1],
                                                    av[s][2], av[s][3]);
        }
    }
}

// ---------- K3: MFMA split-bf16 sim + packed-key top-5 ----------
// ctile: 2 chains (accP 4-deep hi·hi+hi·lo, accQ 2-deep lo·hi) — one v_add
// fewer per candidate than the r17 3-chain form (insert VALU dominates).
__device__ __forceinline__ void ctile(const bf16x8& ah0, const bf16x8& ah1,
                                      const bf16x8& al0, const bf16x8& al1,
                                      const bf16x8& bh0, const bf16x8& bh1,
                                      const bf16x8& bl0, const bf16x8& bl1,
                                      unsigned int (&tk)[4][5], unsigned int inv)
{
    f32x4 accP = {2.0f, 2.0f, 2.0f, 2.0f};   // pack bias pre-seeded
    f32x4 accQ = {0.f, 0.f, 0.f, 0.f};
    accP = __builtin_amdgcn_mfma_f32_16x16x32_bf16(ah0, bh0, accP, 0,0,0);
    accQ = __builtin_amdgcn_mfma_f32_16x16x32_bf16(al0, bh0, accQ, 0,0,0);
    accP = __builtin_amdgcn_mfma_f32_16x16x32_bf16(ah1, bh1, accP, 0,0,0);
    accQ = __builtin_amdgcn_mfma_f32_16x16x32_bf16(al1, bh1, accQ, 0,0,0);
    accP = __builtin_amdgcn_mfma_f32_16x16x32_bf16(ah0, bl0, accP, 0,0,0);
    accP = __builtin_amdgcn_mfma_f32_16x16x32_bf16(ah1, bl1, accP, 0,0,0);
    #pragma unroll
    for (int r = 0; r < 4; ++r) {
        float v = accP[r] + accQ[r];
        unsigned int key = (__float_as_uint(v) & 0xFFFFF000u) | inv;
        ins5k(tk[r], key);
    }
}

__global__ __launch_bounds__(256, 2)
void k_topk(const unsigned short* __restrict__ hl, unsigned int* __restrict__ pk)
{
    int blk = blockIdx.x;
    int cs = blk & 7;
    int rg = (blk >> 3) & 15;
    int b  = blk >> 7;
    int t = threadIdx.x, lane = t & 63, wave = t >> 6;
    int ln = lane & 15, kh = lane >> 4;
    const unsigned short* hb = hl + (size_t)b*NN*128;

    const unsigned short* ap0 = hb + (size_t)(rg*256 + wave*64 + ln)*128 + kh*8;
    bf16x8 a0h0 = *(const bf16x8*)(ap0);
    bf16x8 a0h1 = *(const bf16x8*)(ap0 + 32);
    bf16x8 a0l0 = *(const bf16x8*)(ap0 + 64);
    bf16x8 a0l1 = *(const bf16x8*)(ap0 + 96);
    const unsigned short* ap1 = ap0 + 16*128;
    bf16x8 a1h0 = *(const bf16x8*)(ap1);
    bf16x8 a1h1 = *(const bf16x8*)(ap1 + 32);
    bf16x8 a1l0 = *(const bf16x8*)(ap1 + 64);
    bf16x8 a1l1 = *(const bf16x8*)(ap1 + 96);
    const unsigned short* ap2 = ap0 + 32*128;
    bf16x8 a2h0 = *(const bf16x8*)(ap2);
    bf16x8 a2h1 = *(const bf16x8*)(ap2 + 32);
    bf16x8 a2l0 = *(const bf16x8*)(ap2 + 64);
    bf16x8 a2l1 = *(const bf16x8*)(ap2 + 96);
    const unsigned short* ap3 = ap0 + 48*128;
    bf16x8 a3h0 = *(const bf16x8*)(ap3);
    bf16x8 a3h1 = *(const bf16x8*)(ap3 + 32);
    bf16x8 a3l0 = *(const bf16x8*)(ap3 + 64);
    bf16x8 a3l1 = *(const bf16x8*)(ap3 + 96);

    unsigned int tk0[4][5], tk1[4][5], tk2[4][5], tk3[4][5];
    #pragma unroll
    for (int r=0;r<4;++r)
        #pragma unroll
        for (int kk=0;kk<5;++kk) { tk0[r][kk]=0u; tk1[r][kk]=0u; tk2[r][kk]=0u; tk3[r][kk]=0u; }

    int colbase = cs*512;
    unsigned int inv0 = 4095u - (unsigned int)(colbase + ln);

    const unsigned short* bp = hb + (size_t)(colbase + ln)*128 + kh*8;
    bf16x8 Ah0 = *(const bf16x8*)(bp);
    bf16x8 Ah1 = *(const bf16x8*)(bp + 32);
    bf16x8 Al0 = *(const bf16x8*)(bp + 64);
    bf16x8 Al1 = *(const bf16x8*)(bp + 96);
    bf16x8 Bh0, Bh1, Bl0, Bl1;

    for (int t5 = 0; t5 < 32; t5 += 2) {
        {   // prefetch t5+1
            const unsigned short* p = bp + (size_t)(t5+1)*16*128;
            Bh0 = *(const bf16x8*)(p);
            Bh1 = *(const bf16x8*)(p + 32);
            Bl0 = *(const bf16x8*)(p + 64);
            Bl1 = *(const bf16x8*)(p + 96);
        }
        {
            unsigned int inv = inv0 - (unsigned int)(t5*16);
            ctile(a0h0,a0h1,a0l0,a0l1, Ah0,Ah1,Al0,Al1, tk0, inv);
            ctile(a1h0,a1h1,a1l0,a1l1, Ah0,Ah1,Al0,Al1, tk1, inv);
            ctile(a2h0,a2h1,a2l0,a2l1, Ah0,Ah1,Al0,Al1, tk2, inv);
            ctile(a3h0,a3h1,a3l0,a3l1, Ah0,Ah1,Al0,Al1, tk3, inv);
        }
        {   // prefetch t5+2 (clamped on last iter; dummy, unused)
            int m = (t5+2 < 32) ? (t5+2) : 0;
            const unsigned short* p = bp + (size_t)m*16*128;
            Ah0 = *(const bf16x8*)(p);
            Ah1 = *(const bf16x8*)(p + 32);
            Al0 = *(const bf16x8*)(p + 64);
            Al1 = *(const bf16x8*)(p + 96);
        }
        {
            unsigned int inv = inv0 - (unsigned int)((t5+1)*16);
            ctile(a0h0,a0h1,a0l0,a0l1, Bh0,Bh1,Bl0,Bl1, tk0, inv);
            ctile(a1h0,a1h1,a1l0,a1l1, Bh0,Bh1,Bl0,Bl1, tk1, inv);
            ctile(a2h0,a2h1,a2l0,a2l1, Bh0,Bh1,Bl0,Bl1, tk2, inv);
            ctile(a3h0,a3h1,a3l0,a3l1, Bh0,Bh1,Bl0,Bl1, tk3, inv);
        }
    }

    #pragma unroll
    for (int m = 1; m < 16; m <<= 1) {
        #pragma unroll
        for (int r=0;r<4;++r) {
            unsigned int o0[5], o1[5], o2[5], o3[5];
            #pragma unroll
            for (int kk=0;kk<5;++kk) {
                o0[kk] = (unsigned int)__shfl_xor((int)tk0[r][kk], m);
                o1[kk] = (unsigned int)__shfl_xor((int)tk1[r][kk], m);
                o2[kk] = (unsigned int)__shfl_xor((int)tk2[r][kk], m);
                o3[kk] = (unsigned int)__shfl_xor((int)tk3[r][kk], m);
            }
            #pragma unroll
            for (int kk=0;kk<5;++kk) {
                ins5k(tk0[r], o0[kk]); ins5k(tk1[r], o1[kk]);
                ins5k(tk2[r], o2[kk]); ins5k(tk3[r], o3[kk]);
            }
        }
    }
    if (ln == 0) {
        int rowb = rg*256 + wave*64 + kh*4;
        #pragma unroll
        for (int r=0;r<4;++r) {
            size_t b0 = (((size_t)b*NN + rowb + r)*8 + cs)*5;
            size_t b1 = (((size_t)b*NN + rowb + 16 + r)*8 + cs)*5;
            size_t b2 = (((size_t)b*NN + rowb + 32 + r)*8 + cs)*5;
            size_t b3 = (((size_t)b*NN + rowb + 48 + r)*8 + cs)*5;
            #pragma unroll
            for (int kk=0;kk<5;++kk) {
                pk[b0+kk] = tk0[r][kk]; pk[b1+kk] = tk1[r][kk];
                pk[b2+kk] = tk2[r][kk]; pk[b3+kk] = tk3[r][kk];
            }
        }
    }
}

// ---------- K4: fused top-5 merge + laplacian(k)·laplacian(v) partial reduction ----------
__global__ __launch_bounds__(256) void k_kv(const float* __restrict__ ko, const float* __restrict__ vo,
                                            const unsigned int* __restrict__ pk, float* __restrict__ part)
{
    int blk = blockIdx.x;                 // bh(16) * chunk(32)
    int chunk = blk & 31, bh = blk >> 5, b = bh >> 2;
    int t = threadIdx.x;
    __shared__ int idxl[128][5];
    __shared__ float red[4][64];
    if (t < 128) {
        int n = chunk*128 + t;
        const uint4* pp = (const uint4*)(pk + ((size_t)b*NN + n)*40);
        unsigned int bk5[5] = {0u,0u,0u,0u,0u};
        #pragma unroll
        for (int e = 0; e < 10; ++e) {
            uint4 v4 = pp[e];
            ins5k(bk5, v4.x); ins5k(bk5, v4.y); ins5k(bk5, v4.z); ins5k(bk5, v4.w);
        }
        #pragma unroll
        for (int kk=0;kk<5;++kk) idxl[t][kk] = 4095 - (int)(bk5[kk] & 0xFFFu);
    }
    __syncthreads();
    int f = t & 63, g = t >> 6;
    const float* kb = ko + (size_t)bh*NN*64;
    const float* vb = vo + (size_t)bh*NN*64;
    float acc = 0.f;
    for (int i2 = 0; i2 < 32; ++i2) {
        int nl = g*32 + i2;
        int n = chunk*128 + nl;
        const int* ip = idxl[nl];
        int j0 = ip[0], j1 = ip[1], j2 = ip[2], j3 = ip[3], j4 = ip[4];
        float lk = kb[(size_t)n*64+f] + kb[(size_t)j0*64+f] + kb[(size_t)j1*64+f]
                 + kb[(size_t)j2*64+f] + kb[(size_t)j3*64+f] + kb[(size_t)j4*64+f];
        float lv = vb[(size_t)n*64+f] + vb[(size_t)j0*64+f] + vb[(size_t)j1*64+f]
                 + vb[(size_t)j2*64+f] + vb[(size_t)j3*64+f] + vb[(size_t)j4*64+f];
        acc += lk*lv;
    }
    red[g][f] = acc;
    __syncthreads();
    if (t < 64) {
        float s2 = red[0][t] + red[1][t] + red[2][t] + red[3][t];
        part[((size_t)bh*64 + t)*32 + chunk] = s2;
    }
}

// ---------- K6: fused kv-scale + (hy·wp) conv + conv1/BN/ReLU + conv2/BN/ReLU ----------
// 32-col tiles, grid 512; wp read direct (L1-broadcast) * kvs[] -> no 70KB ws2
// staging for conv_p. LDS ~64.5KB -> 2 blocks/CU (was 157KB, 1/CU).
__global__ __launch_bounds__(256) void k_out(
    const float* __restrict__ qo, const float* __restrict__ wp, const float* __restrict__ part,
    const float* __restrict__ bp,
    const float* __restrict__ w1, const float* __restrict__ b1,
    const float* __restrict__ w2, const float* __restrict__ b2,
    const float* __restrict__ g1, const float* __restrict__ be1,
    const float* __restrict__ m1, const float* __restrict__ v1,
    const float* __restrict__ g2, const float* __restrict__ be2,
    const float* __restrict__ m2, const float* __restrict__ v2,
    float* __restrict__ outp)
{
    int b  = blockIdx.x >> 7;
    int n0 = (blockIdx.x & 127)*32;
    __shared__ __align__(16) float qs[256*36];   // q tile [hf][nl]; later t1 [o][nl]
    __shared__ __align__(16) float ws2[64*68];   // w1s/w2s [c][o]
    __shared__ __align__(16) float t0[64*36];    // conv_p out [o][nl]; later t2
    __shared__ float kvs[256];
    int t = threadIdx.x;
    {
        int f = t & 63, sub = t >> 6;
        #pragma unroll
        for (int h = 0; h < 4; ++h) {
            const float* qb = qo + (((size_t)(b*4+h))*NN + n0)*64 + f;
            for (int nl = sub; nl < 32; nl += 4)
                qs[(h*64+f)*36 + nl] = qb[(size_t)nl*64];
        }
    }
    {   // kv reduction for hf=t
        const float* pp = part + ((size_t)b*256 + t)*32;
        float s = 0.f;
        #pragma unroll
        for (int c2 = 0; c2 < 32; ++c2) s += pp[c2];
        kvs[t] = s * (1.f/36.f);
    }
    __syncthreads();
    int tr = t >> 3, tc = t & 7;      // o block = tr*2+{0,1}; n = tc*4+{0..3}
    float acc[2][4];
    #pragma unroll
    for (int i=0;i<2;++i) {
        float bb = bp[tr*2+i];
        #pragma unroll
        for (int j=0;j<4;++j) acc[i][j] = bb;
    }
    const float* wr0 = wp + (size_t)(tr*2+0)*256;
    const float* wr1 = wp + (size_t)(tr*2+1)*256;
    for (int hfb = 0; hfb < 256; hfb += 4) {
        float4 w04 = *(const float4*)(wr0 + hfb);
        float4 w14 = *(const float4*)(wr1 + hfb);
        float4 kv4 = *(const float4*)&kvs[hfb];
        float w0a[4] = {w04.x, w04.y, w04.z, w04.w};
        float w1a[4] = {w14.x, w14.y, w14.z, w14.w};
        float kva[4] = {kv4.x, kv4.y, kv4.z, kv4.w};
        #pragma unroll
        for (int u = 0; u < 4; ++u) {
            float a0 = w0a[u]*kva[u], a1 = w1a[u]*kva[u];
            float4 b4 = *(const float4*)&qs[(hfb+u)*36 + tc*4];
            acc[0][0] += a0*b4.x; acc[0][1] += a0*b4.y;
            acc[0][2] += a0*b4.z; acc[0][3] += a0*b4.w;
            acc[1][0] += a1*b4.x; acc[1][1] += a1*b4.y;
            acc[1][2] += a1*b4.z; acc[1][3] += a1*b4.w;
        }
    }
    #pragma unroll
    for (int i=0;i<2;++i)
        *(float4*)&t0[(tr*2+i)*36 + tc*4] = make_float4(acc[i][0],acc[i][1],acc[i][2],acc[i][3]);
    __syncthreads();
    #pragma unroll
    for (int s = 0; s < 16; ++s) {   // w1 transposed into ws2
        int e = t + 256*s;
        ws2[(e & 63)*68 + (e >> 6)] = w1[e];
    }
    __syncthreads();
    float acc2[2][4];
    #pragma unroll
    for (int i=0;i<2;++i)
        #pragma unroll
        for (int j=0;j<4;++j) acc2[i][j] = 0.f;
    #pragma unroll 8
    for (int c = 0; c < 64; ++c) {
        float a0 = ws2[c*68 + tr*2];
        float a1 = ws2[c*68 + tr*2 + 1];
        float4 b4 = *(const float4*)&t0[c*36 + tc*4];
        acc2[0][0] += a0*b4.x; acc2[0][1] += a0*b4.y;
        acc2[0][2] += a0*b4.z; acc2[0][3] += a0*b4.w;
        acc2[1][0] += a1*b4.x; acc2[1][1] += a1*b4.y;
        acc2[1][2] += a1*b4.z; acc2[1][3] += a1*b4.w;
    }
    #pragma unroll
    for (int i=0;i<2;++i) {          // BN1 + ReLU -> t1 (in qs region)
        int o = tr*2+i;
        float sc = g1[o] / sqrtf(v1[o] + 1e-5f);
        float bb = b1[o], mm = m1[o], bt = be1[o];
        float4 r;
        r.x = fmaxf((acc2[i][0]+bb-mm)*sc + bt, 0.f);
        r.y = fmaxf((acc2[i][1]+bb-mm)*sc + bt, 0.f);
        r.z = fmaxf((acc2[i][2]+bb-mm)*sc + bt, 0.f);
        r.w = fmaxf((acc2[i][3]+bb-mm)*sc + bt, 0.f);
        *(float4*)&qs[o*36 + tc*4] = r;
    }
    __syncthreads();
    #pragma unroll
    for (int s = 0; s < 16; ++s) {   // w2 transposed into ws2
        int e = t + 256*s;
        ws2[(e & 63)*68 + (e >> 6)] = w2[e];
    }
    __syncthreads();
    float acc3[2][4];
    #pragma unroll
    for (int i=0;i<2;++i)
        #pragma unroll
        for (int j=0;j<4;++j) acc3[i][j] = 0.f;
    #pragma unroll 8
    for (int c = 0; c < 64; ++c) {
        float a0 = ws2[c*68 + tr*2];
        float a1 = ws2[c*68 + tr*2 + 1];
        float4 b4 = *(const float4*)&qs[c*36 + tc*4];
        acc3[0][0] += a0*b4.x; acc3[0][1] += a0*b4.y;
        acc3[0][2] += a0*b4.z; acc3[0][3] += a0*b4.w;
        acc3[1][0] += a1*b4.x; acc3[1][1] += a1*b4.y;
        acc3[1][2] += a1*b4.z; acc3[1][3] += a1*b4.w;
    }
    #pragma unroll
    for (int i=0;i<2;++i) {          // BN2 + ReLU -> t2 (in t0 region)
        int o = tr*2+i;
        float sc = g2[o] / sqrtf(v2[o] + 1e-5f);
        float bb = b2[o], mm = m2[o], bt = be2[o];
        float4 r;
        r.x = fmaxf((acc3[i][0]+bb-mm)*sc + bt, 0.f);
        r.y = fmaxf((acc3[i][1]+bb-mm)*sc + bt, 0.f);
        r.z = fmaxf((acc3[i][2]+bb-mm)*sc + bt, 0.f);
        r.w = fmaxf((acc3[i][3]+bb-mm)*sc + bt, 0.f);
        *(float4*)&t0[o*36 + tc*4] = r;
    }
    __syncthreads();
    float* ob = outp + ((size_t)b*64)*NN + n0;
    #pragma unroll
    for (int s = 0; s < 8; ++s) {
        int e = t + 256*s;
        int o = e >> 5, nl = e & 31;
        ob[(size_t)o*NN + nl] = t0[o*36 + nl];
    }
}

extern "C" void kernel_launch(void* const* d_in, const int* in_sizes, int n_in,
                              void* d_out, int out_size, void* d_ws, size_t ws_size,
                              hipStream_t stream)
{
    (void)in_sizes; (void)n_in; (void)out_size; (void)ws_size;
    const float* x  = (const float*)d_in[0];
    const float* wk = (const float*)d_in[1];
    const float* bk = (const float*)d_in[2];
    const float* wq = (const float*)d_in[3];
    const float* bq = (const float*)d_in[4];
    const float* wv = (const float*)d_in[5];
    const float* bv = (const float*)d_in[6];
    const float* wp = (const float*)d_in[7];
    const float* bp = (const float*)d_in[8];
    const float* w1 = (const float*)d_in[9];
    const float* b1 = (const float*)d_in[10];
    const float* w2 = (const float*)d_in[11];
    const float* b2 = (const float*)d_in[12];
    const float* g1 = (const float*)d_in[13];
    const float* be1= (const float*)d_in[14];
    const float* m1 = (const float*)d_in[15];
    const float* v1 = (const float*)d_in[16];
    const float* g2 = (const float*)d_in[17];
    const float* be2= (const float*)d_in[18];
    const float* m2 = (const float*)d_in[19];
    const float* v2 = (const float*)d_in[20];
    float* out = (float*)d_out;

    float* ws = (float*)d_ws;
    unsigned short* hlb = (unsigned short*)ws;  ws += (size_t)NB*NN*128/2;  // 4MB interleaved hi|lo
    unsigned short* wsb = (unsigned short*)ws;  ws += (size_t)768*128/2;    // 196KB weight split
    float* nrm  = ws;  ws += (size_t)NB*NN;           // 64KB node norms
    float* qbuf = ws;  ws += (size_t)NB*NH*NN*64;     // 16MB
    float* kbuf = ws;  ws += (size_t)NB*NH*NN*64;
    float* vbuf = ws;  ws += (size_t)NB*NH*NN*64;
    float* part = ws;  ws += (size_t)16*64*32;
    unsigned int* pk = (unsigned int*)ws;  ws += (size_t)NB*NN*40;  // 655,360 u32

    k_pre<<<259, 256, 0, stream>>>(x, wk, wq, wv, hlb, nrm, wsb);
    k_qkv<<<768, 256, 0, stream>>>(hlb, nrm, wsb, bk, bq, bv, qbuf, kbuf, vbuf);
    k_topk<<<512, 256, 0, stream>>>(hlb, pk);
    k_kv<<<512, 256, 0, stream>>>(kbuf, vbuf, pk, part);
    k_out<<<512, 256, 0, stream>>>(qbuf, wp, part, bp, w1,b1, w2,b2,
                                   g1,be1,m1,v1, g2,be2,m2,v2, out);
}

// Round 21
// 124.722 us; speedup vs baseline: 1.2877x; 1.1111x over previous
//
#include <hip/hip_runtime.h>
#include <math.h>

#define NB 4
#define NC 64
#define NN 4096
#define NH 4

typedef __attribute__((ext_vector_type(8))) short bf16x8;
typedef __attribute__((ext_vector_type(4))) float f32x4;

// ---------- RNE float -> bf16 bits ----------
__device__ __forceinline__ unsigned int bf16rne(float v) {
    unsigned int u = __float_as_uint(v);
    return (u + 0x7fffu + ((u >> 16) & 1u)) >> 16;
}

// ---------- top-4 insert (7 VALU) ----------
__device__ __forceinline__ void ins4k(unsigned int (&tk)[4], unsigned int key) {
    unsigned int n0 = max(tk[0], key);
    unsigned int n1 = min(tk[0], max(tk[1], key));
    unsigned int n2 = min(tk[1], max(tk[2], key));
    unsigned int n3 = min(tk[2], max(tk[3], key));
    tk[0]=n0; tk[1]=n1; tk[2]=n2; tk[3]=n3;
}

// ---------- split helper: 8 floats -> hi uint4 + lo uint4 ----------
__device__ __forceinline__ void split8(const float* v, uint4& hw4, uint4& lw4) {
    unsigned int hw[4], lw[4];
    #pragma unroll
    for (int p = 0; p < 4; ++p) {
        float v0 = v[p*2], v1 = v[p*2+1];
        unsigned int h0 = bf16rne(v0), h1 = bf16rne(v1);
        float r0 = v0 - __uint_as_float(h0 << 16);
        float r1 = v1 - __uint_as_float(h1 << 16);
        unsigned int l0 = bf16rne(r0), l1 = bf16rne(r1);
        hw[p] = h0 | (h1 << 16);
        lw[p] = l0 | (l1 << 16);
    }
    hw4 = make_uint4(hw[0], hw[1], hw[2], hw[3]);
    lw4 = make_uint4(lw[0], lw[1], lw[2], lw[3]);
}

// ---------- K0: xsplit (4 waves/64-node group) + nrm + weight split ----------
__global__ __launch_bounds__(256) void k_pre(
    const float* __restrict__ x,
    const float* __restrict__ wk, const float* __restrict__ wq, const float* __restrict__ wv,
    unsigned short* __restrict__ hl, float* __restrict__ nrm,
    unsigned short* __restrict__ wsb)
{
    __shared__ float redn[4][64];
    int blk = blockIdx.x;
    int t = threadIdx.x;
    if (blk >= 256) {   // ---- weight split ----
        int r = (blk - 256)*256 + t;     // 0..767
        int mat = r >> 8, oc = r & 255;
        const float* wsrc = (mat==0) ? wk : ((mat==1) ? wq : wv);
        float wrow[64];
        #pragma unroll
        for (int g = 0; g < 16; ++g)
            *(float4*)&wrow[g*4] = *(const float4*)(wsrc + (size_t)oc*64 + g*4);
        unsigned short* wo = wsb + (size_t)r*128;
        #pragma unroll
        for (int g = 0; g < 8; ++g) {
            uint4 hw4, lw4;
            split8(&wrow[g*8], hw4, lw4);
            *(uint4*)(wo + g*8)      = hw4;
            *(uint4*)(wo + 64 + g*8) = lw4;
        }
        return;
    }
    // ---- xsplit ----
    int lane = t & 63, g = t >> 6;
    int node = blk*64 + lane;
    const float* xb = x + ((size_t)(node >> 12))*NC*NN + (node & (NN-1));
    float vals[16];
    float ss = 0.f;
    #pragma unroll
    for (int i = 0; i < 16; ++i) {
        vals[i] = xb[(size_t)(g*16 + i)*NN];
        ss += vals[i]*vals[i];
    }
    redn[g][lane] = ss;
    __syncthreads();
    float st = redn[0][lane] + redn[1][lane] + redn[2][lane] + redn[3][lane];
    float rn = 1.f / fmaxf(sqrtf(st), 1e-12f);
    if (g == 0) nrm[node] = sqrtf(st);
    float nv[16];
    #pragma unroll
    for (int i = 0; i < 16; ++i) nv[i] = vals[i] * rn;
    unsigned short* ho = hl + (size_t)node*128 + g*16;
    #pragma unroll
    for (int gg = 0; gg < 2; ++gg) {
        uint4 hw4, lw4;
        split8(&nv[gg*8], hw4, lw4);
        *(uint4*)(ho + gg*8)      = hw4;
        *(uint4*)(ho + 64 + gg*8) = lw4;
    }
}

// ---------- K2: MFMA q/k/v projections from hlb (W·x = nrm·(W·xn)) ----------
__global__ __launch_bounds__(256, 2) void k_qkv(
    const unsigned short* __restrict__ hl, const float* __restrict__ nrm,
    const unsigned short* __restrict__ wsb,
    const float* __restrict__ bk, const float* __restrict__ bq, const float* __restrict__ bv,
    float* __restrict__ qo, float* __restrict__ ko, float* __restrict__ vo)
{
    int blk = blockIdx.x;
    int nt  = blk & 63;
    int rem = blk >> 6;          // 0..11
    int mat = rem % 3, b = rem / 3;
    const float* bias = (mat==0) ? bk : ((mat==1) ? bq : bv);
    float* outp       = (mat==0) ? ko : ((mat==1) ? qo : vo);
    int t = threadIdx.x, lane = t & 63, h = t >> 6;
    int ln = lane & 15, kh = lane >> 4;

    bf16x8 ah0[4], ah1[4], al0[4], al1[4];
    const unsigned short* wb2 = wsb + ((size_t)(mat*256 + h*64 + ln))*128 + kh*8;
    #pragma unroll
    for (int s = 0; s < 4; ++s) {
        const unsigned short* p = wb2 + (size_t)s*16*128;
        ah0[s] = *(const bf16x8*)(p);
        ah1[s] = *(const bf16x8*)(p + 32);
        al0[s] = *(const bf16x8*)(p + 64);
        al1[s] = *(const bf16x8*)(p + 96);
    }
    float4 bj[4];
    #pragma unroll
    for (int s = 0; s < 4; ++s) bj[s] = *(const float4*)(bias + h*64 + s*16 + kh*4);

    int n0base = nt*64;
    const unsigned short* xb2 = hl + ((size_t)b*NN + n0base + ln)*128 + kh*8;
    #pragma unroll
    for (int j = 0; j < 4; ++j) {
        const unsigned short* p = xb2 + (size_t)j*16*128;
        bf16x8 bh0 = *(const bf16x8*)(p);
        bf16x8 bh1 = *(const bf16x8*)(p + 32);
        bf16x8 bl0 = *(const bf16x8*)(p + 64);
        bf16x8 bl1 = *(const bf16x8*)(p + 96);
        int n = n0base + j*16 + ln;
        float sc = nrm[(size_t)b*NN + n];
        f32x4 av[4];
        #pragma unroll
        for (int s = 0; s < 4; ++s) {
            f32x4 acc = {0.f, 0.f, 0.f, 0.f};
            acc = __builtin_amdgcn_mfma_f32_16x16x32_bf16(ah0[s], bh0, acc, 0,0,0);
            acc = __builtin_amdgcn_mfma_f32_16x16x32_bf16(ah1[s], bh1, acc, 0,0,0);
            acc = __builtin_amdgcn_mfma_f32_16x16x32_bf16(al0[s], bh0, acc, 0,0,0);
            acc = __builtin_amdgcn_mfma_f32_16x16x32_bf16(al1[s], bh1, acc, 0,0,0);
            acc = __builtin_amdgcn_mfma_f32_16x16x32_bf16(ah0[s], bl0, acc, 0,0,0);
            acc = __builtin_amdgcn_mfma_f32_16x16x32_bf16(ah1[s], bl1, acc, 0,0,0);
            av[s][0] = acc[0]*sc + bj[s].x;
            av[s][1] = acc[1]*sc + bj[s].y;
            av[s][2] = acc[2]*sc + bj[s].z;
            av[s][3] = acc[3]*sc + bj[s].w;
        }
        float* ob = outp + (((size_t)(b*NH + h))*NN + n)*64 + kh*4;
        if (mat != 2) {
            float ss = 0.f;
            #pragma unroll
            for (int s = 0; s < 4; ++s)
                ss += av[s][0]*av[s][0] + av[s][1]*av[s][1]
                    + av[s][2]*av[s][2] + av[s][3]*av[s][3];
            ss += __shfl_xor(ss, 16);
            ss += __shfl_xor(ss, 32);
            float rn = 1.f / fmaxf(sqrtf(ss), 1e-12f);
            #pragma unroll
            for (int s = 0; s < 4; ++s)
                *(float4*)(ob + s*16) = make_float4(av[s][0]*rn, av[s][1]*rn,
                                                    av[s][2]*rn, av[s][3]*rn);
        } else {
            #pragma unroll
            for (int s = 0; s < 4; ++s)
                *(float4*)(ob + s*16) = make_float4(av[s][0], av[s][1],
                                                    av[s][2], av[s][3]);
        }
    }
}

// ---------- K3: MFMA split-bf16 sim + packed-key top-4 (self excluded) ----------
// Self-sim is always the row max, so ref top-5 = {self} ∪ top-4-off-diag;
// k_kv adds self twice. Diagonal masked via dk[] only in the (rare) diag tiles.
__device__ __forceinline__ void ctile4(const bf16x8& ah0, const bf16x8& ah1,
                                       const bf16x8& al0, const bf16x8& al1,
                                       const bf16x8& bh0, const bf16x8& bh1,
                                       const bf16x8& bl0, const bf16x8& bl1,
                                       unsigned int (&tk)[4][4], unsigned int inv)
{
    f32x4 accP = {2.0f, 2.0f, 2.0f, 2.0f};   // pack bias pre-seeded
    f32x4 accQ = {0.f, 0.f, 0.f, 0.f};
    accP = __builtin_amdgcn_mfma_f32_16x16x32_bf16(ah0, bh0, accP, 0,0,0);
    accQ = __builtin_amdgcn_mfma_f32_16x16x32_bf16(al0, bh0, accQ, 0,0,0);
    accP = __builtin_amdgcn_mfma_f32_16x16x32_bf16(ah1, bh1, accP, 0,0,0);
    accQ = __builtin_amdgcn_mfma_f32_16x16x32_bf16(al1, bh1, accQ, 0,0,0);
    accP = __builtin_amdgcn_mfma_f32_16x16x32_bf16(ah0, bl0, accP, 0,0,0);
    accP = __builtin_amdgcn_mfma_f32_16x16x32_bf16(ah1, bl1, accP, 0,0,0);
    #pragma unroll
    for (int r = 0; r < 4; ++r) {
        float v = accP[r] + accQ[r];
        unsigned int key = (__float_as_uint(v) & 0xFFFFF000u) | inv;
        ins4k(tk[r], key);
    }
}

__device__ __forceinline__ void ctile4d(const bf16x8& ah0, const bf16x8& ah1,
                                        const bf16x8& al0, const bf16x8& al1,
                                        const bf16x8& bh0, const bf16x8& bh1,
                                        const bf16x8& bl0, const bf16x8& bl1,
                                        unsigned int (&tk)[4][4], unsigned int inv,
                                        const unsigned int (&dk)[4])
{
    f32x4 accP = {2.0f, 2.0f, 2.0f, 2.0f};
    f32x4 accQ = {0.f, 0.f, 0.f, 0.f};
    accP = __builtin_amdgcn_mfma_f32_16x16x32_bf16(ah0, bh0, accP, 0,0,0);
    accQ = __builtin_amdgcn_mfma_f32_16x16x32_bf16(al0, bh0, accQ, 0,0,0);
    accP = __builtin_amdgcn_mfma_f32_16x16x32_bf16(ah1, bh1, accP, 0,0,0);
    accQ = __builtin_amdgcn_mfma_f32_16x16x32_bf16(al1, bh1, accQ, 0,0,0);
    accP = __builtin_amdgcn_mfma_f32_16x16x32_bf16(ah0, bl0, accP, 0,0,0);
    accP = __builtin_amdgcn_mfma_f32_16x16x32_bf16(ah1, bl1, accP, 0,0,0);
    #pragma unroll
    for (int r = 0; r < 4; ++r) {
        float v = accP[r] + accQ[r];
        unsigned int key = ((__float_as_uint(v) & 0xFFFFF000u) | inv) & dk[r];
        ins4k(tk[r], key);
    }
}

__global__ __launch_bounds__(256, 2)
void k_topk(const unsigned short* __restrict__ hl, unsigned int* __restrict__ pk)
{
    int blk = blockIdx.x;
    int cs = blk & 7;
    int rg = (blk >> 3) & 15;
    int b  = blk >> 7;
    int t = threadIdx.x, lane = t & 63, wave = t >> 6;
    int ln = lane & 15, kh = lane >> 4;
    const unsigned short* hb = hl + (size_t)b*NN*128;

    const unsigned short* ap0 = hb + (size_t)(rg*256 + wave*64 + ln)*128 + kh*8;
    bf16x8 a0h0 = *(const bf16x8*)(ap0);
    bf16x8 a0h1 = *(const bf16x8*)(ap0 + 32);
    bf16x8 a0l0 = *(const bf16x8*)(ap0 + 64);
    bf16x8 a0l1 = *(const bf16x8*)(ap0 + 96);
    const unsigned short* ap1 = ap0 + 16*128;
    bf16x8 a1h0 = *(const bf16x8*)(ap1);
    bf16x8 a1h1 = *(const bf16x8*)(ap1 + 32);
    bf16x8 a1l0 = *(const bf16x8*)(ap1 + 64);
    bf16x8 a1l1 = *(const bf16x8*)(ap1 + 96);
    const unsigned short* ap2 = ap0 + 32*128;
    bf16x8 a2h0 = *(const bf16x8*)(ap2);
    bf16x8 a2h1 = *(const bf16x8*)(ap2 + 32);
    bf16x8 a2l0 = *(const bf16x8*)(ap2 + 64);
    bf16x8 a2l1 = *(const bf16x8*)(ap2 + 96);
    const unsigned short* ap3 = ap0 + 48*128;
    bf16x8 a3h0 = *(const bf16x8*)(ap3);
    bf16x8 a3h1 = *(const bf16x8*)(ap3 + 32);
    bf16x8 a3l0 = *(const bf16x8*)(ap3 + 64);
    bf16x8 a3l1 = *(const bf16x8*)(ap3 + 96);

    unsigned int tk0[4][4], tk1[4][4], tk2[4][4], tk3[4][4];
    #pragma unroll
    for (int r=0;r<4;++r)
        #pragma unroll
        for (int kk=0;kk<4;++kk) { tk0[r][kk]=0u; tk1[r][kk]=0u; tk2[r][kk]=0u; tk3[r][kk]=0u; }

    int colbase = cs*512;
    unsigned int inv0 = 4095u - (unsigned int)(colbase + ln);

    // diagonal bookkeeping: this block touches the diagonal iff (rg>>1)==cs.
    // per strip exactly one 16-col tile (dtS) contains diag; mask row==col there.
    int dgb = ((rg >> 1) == cs);
    int base0 = rg*256 + wave*64;
    int dt0 = dgb ? ((base0      - colbase) >> 4) : -1;
    int dt1 = dgb ? ((base0 + 16 - colbase) >> 4) : -1;
    int dt2 = dgb ? ((base0 + 32 - colbase) >> 4) : -1;
    int dt3 = dgb ? ((base0 + 48 - colbase) >> 4) : -1;
    unsigned int dk[4];
    #pragma unroll
    for (int r=0;r<4;++r) dk[r] = ((kh*4 + r) == ln) ? 0u : 0xFFFFFFFFu;

    const unsigned short* bp = hb + (size_t)(colbase + ln)*128 + kh*8;
    bf16x8 Ah0 = *(const bf16x8*)(bp);
    bf16x8 Ah1 = *(const bf16x8*)(bp + 32);
    bf16x8 Al0 = *(const bf16x8*)(bp + 64);
    bf16x8 Al1 = *(const bf16x8*)(bp + 96);
    bf16x8 Bh0, Bh1, Bl0, Bl1;

    for (int t5 = 0; t5 < 32; t5 += 2) {
        {   // prefetch t5+1
            const unsigned short* p = bp + (size_t)(t5+1)*16*128;
            Bh0 = *(const bf16x8*)(p);
            Bh1 = *(const bf16x8*)(p + 32);
            Bl0 = *(const bf16x8*)(p + 64);
            Bl1 = *(const bf16x8*)(p + 96);
        }
        {
            unsigned int inv = inv0 - (unsigned int)(t5*16);
            if (t5 == dt0) ctile4d(a0h0,a0h1,a0l0,a0l1, Ah0,Ah1,Al0,Al1, tk0, inv, dk);
            else           ctile4 (a0h0,a0h1,a0l0,a0l1, Ah0,Ah1,Al0,Al1, tk0, inv);
            if (t5 == dt1) ctile4d(a1h0,a1h1,a1l0,a1l1, Ah0,Ah1,Al0,Al1, tk1, inv, dk);
            else           ctile4 (a1h0,a1h1,a1l0,a1l1, Ah0,Ah1,Al0,Al1, tk1, inv);
            if (t5 == dt2) ctile4d(a2h0,a2h1,a2l0,a2l1, Ah0,Ah1,Al0,Al1, tk2, inv, dk);
            else           ctile4 (a2h0,a2h1,a2l0,a2l1, Ah0,Ah1,Al0,Al1, tk2, inv);
            if (t5 == dt3) ctile4d(a3h0,a3h1,a3l0,a3l1, Ah0,Ah1,Al0,Al1, tk3, inv, dk);
            else           ctile4 (a3h0,a3h1,a3l0,a3l1, Ah0,Ah1,Al0,Al1, tk3, inv);
        }
        {   // prefetch t5+2 (clamped on last iter; dummy, unused)
            int m = (t5+2 < 32) ? (t5+2) : 0;
            const unsigned short* p = bp + (size_t)m*16*128;
            Ah0 = *(const bf16x8*)(p);
            Ah1 = *(const bf16x8*)(p + 32);
            Al0 = *(const bf16x8*)(p + 64);
            Al1 = *(const bf16x8*)(p + 96);
        }
        {
            int t5b = t5 + 1;
            unsigned int inv = inv0 - (unsigned int)(t5b*16);
            if (t5b == dt0) ctile4d(a0h0,a0h1,a0l0,a0l1, Bh0,Bh1,Bl0,Bl1, tk0, inv, dk);
            else            ctile4 (a0h0,a0h1,a0l0,a0l1, Bh0,Bh1,Bl0,Bl1, tk0, inv);
            if (t5b == dt1) ctile4d(a1h0,a1h1,a1l0,a1l1, Bh0,Bh1,Bl0,Bl1, tk1, inv, dk);
            else            ctile4 (a1h0,a1h1,a1l0,a1l1, Bh0,Bh1,Bl0,Bl1, tk1, inv);
            if (t5b == dt2) ctile4d(a2h0,a2h1,a2l0,a2l1, Bh0,Bh1,Bl0,Bl1, tk2, inv, dk);
            else            ctile4 (a2h0,a2h1,a2l0,a2l1, Bh0,Bh1,Bl0,Bl1, tk2, inv);
            if (t5b == dt3) ctile4d(a3h0,a3h1,a3l0,a3l1, Bh0,Bh1,Bl0,Bl1, tk3, inv, dk);
            else            ctile4 (a3h0,a3h1,a3l0,a3l1, Bh0,Bh1,Bl0,Bl1, tk3, inv);
        }
    }

    // butterfly merge across the 16 column-lanes (lane bits 0..3 = ln)
    #pragma unroll
    for (int m = 1; m < 16; m <<= 1) {
        #pragma unroll
        for (int r=0;r<4;++r) {
            unsigned int o0[4], o1[4], o2[4], o3[4];
            #pragma unroll
            for (int kk=0;kk<4;++kk) {
                o0[kk] = (unsigned int)__shfl_xor((int)tk0[r][kk], m);
                o1[kk] = (unsigned int)__shfl_xor((int)tk1[r][kk], m);
                o2[kk] = (unsigned int)__shfl_xor((int)tk2[r][kk], m);
                o3[kk] = (unsigned int)__shfl_xor((int)tk3[r][kk], m);
            }
            #pragma unroll
            for (int kk=0;kk<4;++kk) {
                ins4k(tk0[r], o0[kk]); ins4k(tk1[r], o1[kk]);
                ins4k(tk2[r], o2[kk]); ins4k(tk3[r], o3[kk]);
            }
        }
    }
    if (ln == 0) {
        int rowb = rg*256 + wave*64 + kh*4;
        #pragma unroll
        for (int r=0;r<4;++r) {
            *(uint4*)(pk + (((size_t)b*NN + rowb + r)*8 + cs)*4)
                = make_uint4(tk0[r][0], tk0[r][1], tk0[r][2], tk0[r][3]);
            *(uint4*)(pk + (((size_t)b*NN + rowb + 16 + r)*8 + cs)*4)
                = make_uint4(tk1[r][0], tk1[r][1], tk1[r][2], tk1[r][3]);
            *(uint4*)(pk + (((size_t)b*NN + rowb + 32 + r)*8 + cs)*4)
                = make_uint4(tk2[r][0], tk2[r][1], tk2[r][2], tk2[r][3]);
            *(uint4*)(pk + (((size_t)b*NN + rowb + 48 + r)*8 + cs)*4)
                = make_uint4(tk3[r][0], tk3[r][1], tk3[r][2], tk3[r][3]);
        }
    }
}

// ---------- K4: fused top-4 merge + laplacian(k)·laplacian(v) partial reduction ----------
// lk = k[n] + k[n] + 4 off-diag neighbors == old k[n] + top5(incl self) sequence.
__global__ __launch_bounds__(256) void k_kv(const float* __restrict__ ko, const float* __restrict__ vo,
                                            const unsigned int* __restrict__ pk, float* __restrict__ part)
{
    int blk = blockIdx.x;                 // bh(16) * chunk(32)
    int chunk = blk & 31, bh = blk >> 5, b = bh >> 2;
    int t = threadIdx.x;
    __shared__ int idxl[128][4];
    __shared__ float red[4][64];
    if (t < 128) {
        int n = chunk*128 + t;
        const uint4* pp = (const uint4*)(pk + ((size_t)b*NN + n)*32);
        unsigned int bk4[4] = {0u,0u,0u,0u};
        #pragma unroll
        for (int e = 0; e < 8; ++e) {
            uint4 v4 = pp[e];
            ins4k(bk4, v4.x); ins4k(bk4, v4.y); ins4k(bk4, v4.z); ins4k(bk4, v4.w);
        }
        #pragma unroll
        for (int kk=0;kk<4;++kk) idxl[t][kk] = 4095 - (int)(bk4[kk] & 0xFFFu);
    }
    __syncthreads();
    int f = t & 63, g = t >> 6;
    const float* kb = ko + (size_t)bh*NN*64;
    const float* vb = vo + (size_t)bh*NN*64;
    float acc = 0.f;
    for (int i2 = 0; i2 < 32; ++i2) {
        int nl = g*32 + i2;
        int n = chunk*128 + nl;
        const int* ip = idxl[nl];
        int j0 = ip[0], j1 = ip[1], j2 = ip[2], j3 = ip[3];
        float kn = kb[(size_t)n*64+f];
        float vn = vb[(size_t)n*64+f];
        float lk = kn + kn + kb[(size_t)j0*64+f] + kb[(size_t)j1*64+f]
                 + kb[(size_t)j2*64+f] + kb[(size_t)j3*64+f];
        float lv = vn + vn + vb[(size_t)j0*64+f] + vb[(size_t)j1*64+f]
                 + vb[(size_t)j2*64+f] + vb[(size_t)j3*64+f];
        acc += lk*lv;
    }
    red[g][f] = acc;
    __syncthreads();
    if (t < 64) {
        float s2 = red[0][t] + red[1][t] + red[2][t] + red[3][t];
        part[((size_t)bh*64 + t)*32 + chunk] = s2;
    }
}

// ---------- K6: fused kv-scale + (hy·wp) conv + conv1/BN/ReLU + conv2/BN/ReLU ----------
// 32-col tiles, grid 512; wp read direct * kvs[] -> LDS ~64.5KB, 2 blocks/CU.
__global__ __launch_bounds__(256) void k_out(
    const float* __restrict__ qo, const float* __restrict__ wp, const float* __restrict__ part,
    const float* __restrict__ bp,
    const float* __restrict__ w1, const float* __restrict__ b1,
    const float* __restrict__ w2, const float* __restrict__ b2,
    const float* __restrict__ g1, const float* __restrict__ be1,
    const float* __restrict__ m1, const float* __restrict__ v1,
    const float* __restrict__ g2, const float* __restrict__ be2,
    const float* __restrict__ m2, const float* __restrict__ v2,
    float* __restrict__ outp)
{
    int b  = blockIdx.x >> 7;
    int n0 = (blockIdx.x & 127)*32;
    __shared__ __align__(16) float qs[256*36];   // q tile [hf][nl]; later t1 [o][nl]
    __shared__ __align__(16) float ws2[64*68];   // w1s/w2s [c][o]
    __shared__ __align__(16) float t0[64*36];    // conv_p out [o][nl]; later t2
    __shared__ float kvs[256];
    int t = threadIdx.x;
    {
        int f = t & 63, sub = t >> 6;
        #pragma unroll
        for (int h = 0; h < 4; ++h) {
            const float* qb = qo + (((size_t)(b*4+h))*NN + n0)*64 + f;
            for (int nl = sub; nl < 32; nl += 4)
                qs[(h*64+f)*36 + nl] = qb[(size_t)nl*64];
        }
    }
    {   // kv reduction for hf=t
        const float* pp = part + ((size_t)b*256 + t)*32;
        float s = 0.f;
        #pragma unroll
        for (int c2 = 0; c2 < 32; ++c2) s += pp[c2];
        kvs[t] = s * (1.f/36.f);
    }
    __syncthreads();
    int tr = t >> 3, tc = t & 7;      // o block = tr*2+{0,1}; n = tc*4+{0..3}
    float acc[2][4];
    #pragma unroll
    for (int i=0;i<2;++i) {
        float bb = bp[tr*2+i];
        #pragma unroll
        for (int j=0;j<4;++j) acc[i][j] = bb;
    }
    const float* wr0 = wp + (size_t)(tr*2+0)*256;
    const float* wr1 = wp + (size_t)(tr*2+1)*256;
    for (int hfb = 0; hfb < 256; hfb += 4) {
        float4 w04 = *(const float4*)(wr0 + hfb);
        float4 w14 = *(const float4*)(wr1 + hfb);
        float4 kv4 = *(const float4*)&kvs[hfb];
        float w0a[4] = {w04.x, w04.y, w04.z, w04.w};
        float w1a[4] = {w14.x, w14.y, w14.z, w14.w};
        float kva[4] = {kv4.x, kv4.y, kv4.z, kv4.w};
        #pragma unroll
        for (int u = 0; u < 4; ++u) {
            float a0 = w0a[u]*kva[u], a1 = w1a[u]*kva[u];
            float4 b4 = *(const float4*)&qs[(hfb+u)*36 + tc*4];
            acc[0][0] += a0*b4.x; acc[0][1] += a0*b4.y;
            acc[0][2] += a0*b4.z; acc[0][3] += a0*b4.w;
            acc[1][0] += a1*b4.x; acc[1][1] += a1*b4.y;
            acc[1][2] += a1*b4.z; acc[1][3] += a1*b4.w;
        }
    }
    #pragma unroll
    for (int i=0;i<2;++i)
        *(float4*)&t0[(tr*2+i)*36 + tc*4] = make_float4(acc[i][0],acc[i][1],acc[i][2],acc[i][3]);
    __syncthreads();
    #pragma unroll
    for (int s = 0; s < 16; ++s) {   // w1 transposed into ws2
        int e = t + 256*s;
        ws2[(e & 63)*68 + (e >> 6)] = w1[e];
    }
    __syncthreads();
    float acc2[2][4];
    #pragma unroll
    for (int i=0;i<2;++i)
        #pragma unroll
        for (int j=0;j<4;++j) acc2[i][j] = 0.f;
    #pragma unroll 8
    for (int c = 0; c < 64; ++c) {
        float a0 = ws2[c*68 + tr*2];
        float a1 = ws2[c*68 + tr*2 + 1];
        float4 b4 = *(const float4*)&t0[c*36 + tc*4];
        acc2[0][0] += a0*b4.x; acc2[0][1] += a0*b4.y;
        acc2[0][2] += a0*b4.z; acc2[0][3] += a0*b4.w;
        acc2[1][0] += a1*b4.x; acc2[1][1] += a1*b4.y;
        acc2[1][2] += a1*b4.z; acc2[1][3] += a1*b4.w;
    }
    #pragma unroll
    for (int i=0;i<2;++i) {          // BN1 + ReLU -> t1 (in qs region)
        int o = tr*2+i;
        float sc = g1[o] / sqrtf(v1[o] + 1e-5f);
        float bb = b1[o], mm = m1[o], bt = be1[o];
        float4 r;
        r.x = fmaxf((acc2[i][0]+bb-mm)*sc + bt, 0.f);
        r.y = fmaxf((acc2[i][1]+bb-mm)*sc + bt, 0.f);
        r.z = fmaxf((acc2[i][2]+bb-mm)*sc + bt, 0.f);
        r.w = fmaxf((acc2[i][3]+bb-mm)*sc + bt, 0.f);
        *(float4*)&qs[o*36 + tc*4] = r;
    }
    __syncthreads();
    #pragma unroll
    for (int s = 0; s < 16; ++s) {   // w2 transposed into ws2
        int e = t + 256*s;
        ws2[(e & 63)*68 + (e >> 6)] = w2[e];
    }
    __syncthreads();
    float acc3[2][4];
    #pragma unroll
    for (int i=0;i<2;++i)
        #pragma unroll
        for (int j=0;j<4;++j) acc3[i][j] = 0.f;
    #pragma unroll 8
    for (int c = 0; c < 64; ++c) {
        float a0 = ws2[c*68 + tr*2];
        float a1 = ws2[c*68 + tr*2 + 1];
        float4 b4 = *(const float4*)&qs[c*36 + tc*4];
        acc3[0][0] += a0*b4.x; acc3[0][1] += a0*b4.y;
        acc3[0][2] += a0*b4.z; acc3[0][3] += a0*b4.w;
        acc3[1][0] += a1*b4.x; acc3[1][1] += a1*b4.y;
        acc3[1][2] += a1*b4.z; acc3[1][3] += a1*b4.w;
    }
    #pragma unroll
    for (int i=0;i<2;++i) {          // BN2 + ReLU -> t2 (in t0 region)
        int o = tr*2+i;
        float sc = g2[o] / sqrtf(v2[o] + 1e-5f);
        float bb = b2[o], mm = m2[o], bt = be2[o];
        float4 r;
        r.x = fmaxf((acc3[i][0]+bb-mm)*sc + bt, 0.f);
        r.y = fmaxf((acc3[i][1]+bb-mm)*sc + bt, 0.f);
        r.z = fmaxf((acc3[i][2]+bb-mm)*sc + bt, 0.f);
        r.w = fmaxf((acc3[i][3]+bb-mm)*sc + bt, 0.f);
        *(float4*)&t0[o*36 + tc*4] = r;
    }
    __syncthreads();
    float* ob = outp + ((size_t)b*64)*NN + n0;
    #pragma unroll
    for (int s = 0; s < 8; ++s) {
        int e = t + 256*s;
        int o = e >> 5, nl = e & 31;
        ob[(size_t)o*NN + nl] = t0[o*36 + nl];
    }
}

extern "C" void kernel_launch(void* const* d_in, const int* in_sizes, int n_in,
                              void* d_out, int out_size, void* d_ws, size_t ws_size,
                              hipStream_t stream)
{
    (void)in_sizes; (void)n_in; (void)out_size; (void)ws_size;
    const float* x  = (const float*)d_in[0];
    const float* wk = (const float*)d_in[1];
    const float* bk = (const float*)d_in[2];
    const float* wq = (const float*)d_in[3];
    const float* bq = (const float*)d_in[4];
    const float* wv = (const float*)d_in[5];
    const float* bv = (const float*)d_in[6];
    const float* wp = (const float*)d_in[7];
    const float* bp = (const float*)d_in[8];
    const float* w1 = (const float*)d_in[9];
    const float* b1 = (const float*)d_in[10];
    const float* w2 = (const float*)d_in[11];
    const float* b2 = (const float*)d_in[12];
    const float* g1 = (const float*)d_in[13];
    const float* be1= (const float*)d_in[14];
    const float* m1 = (const float*)d_in[15];
    const float* v1 = (const float*)d_in[16];
    const float* g2 = (const float*)d_in[17];
    const float* be2= (const float*)d_in[18];
    const float* m2 = (const float*)d_in[19];
    const float* v2 = (const float*)d_in[20];
    float* out = (float*)d_out;

    float* ws = (float*)d_ws;
    unsigned short* hlb = (unsigned short*)ws;  ws += (size_t)NB*NN*128/2;  // 4MB interleaved hi|lo
    unsigned short* wsb = (unsigned short*)ws;  ws += (size_t)768*128/2;    // 196KB weight split
    float* nrm  = ws;  ws += (size_t)NB*NN;           // 64KB node norms
    float* qbuf = ws;  ws += (size_t)NB*NH*NN*64;     // 16MB
    float* kbuf = ws;  ws += (size_t)NB*NH*NN*64;
    float* vbuf = ws;  ws += (size_t)NB*NH*NN*64;
    float* part = ws;  ws += (size_t)16*64*32;
    unsigned int* pk = (unsigned int*)ws;  ws += (size_t)NB*NN*32;  // 524,288 u32

    k_pre<<<259, 256, 0, stream>>>(x, wk, wq, wv, hlb, nrm, wsb);
    k_qkv<<<768, 256, 0, stream>>>(hlb, nrm, wsb, bk, bq, bv, qbuf, kbuf, vbuf);
    k_topk<<<512, 256, 0, stream>>>(hlb, pk);
    k_kv<<<512, 256, 0, stream>>>(kbuf, vbuf, pk, part);
    k_out<<<512, 256, 0, stream>>>(qbuf, wp, part, bp, w1,b1, w2,b2,
                                   g1,be1,m1,v1, g2,be2,m2,v2, out);
}